// Round 15
// baseline (517.750 us; speedup 1.0000x reference)
//
#include <hip/hip_runtime.h>
#include <hip/hip_bf16.h>
#include <math.h>
#include <stdint.h>

#define T_ 197
#define B_ 64
#define F_ 768
#define N_ 8
#define CAP_ 49
#define H_ 3072
#define G_ 192
#define TB_ (T_*B_)       // 12608
#define NBN_ (B_*N_)      // 512
#define ME_ 3200          // padded rows per expert (25 * 128)
#define MR_ 3136          // real rows per expert (64 * 49)
#define MT_ 25600         // total padded rows
#define KH_ 4             // gate1 K-split
#define HP_ 768           // tier-B GEMM H-pass chunk
#define HCF_ 384          // fallback (round-1) H chunk
#define NPF_ 8

using bf16x8 = __attribute__((ext_vector_type(8))) short;
using f32x4  = __attribute__((ext_vector_type(4))) float;

__device__ __forceinline__ unsigned short f2bf(float v) {
    __hip_bfloat16 h = __float2bfloat16(v);
    return __builtin_bit_cast(unsigned short, h);
}
__device__ __forceinline__ float bf2f(unsigned short u) {
    unsigned int w = ((unsigned int)u) << 16;
    return __builtin_bit_cast(float, w);
}
__device__ __forceinline__ unsigned int add2bf(unsigned int a, unsigned int b) {
    float al = bf2f((unsigned short)(a & 0xffff)), ah = bf2f((unsigned short)(a >> 16));
    float bl = bf2f((unsigned short)(b & 0xffff)), bh = bf2f((unsigned short)(b >> 16));
    return (unsigned int)f2bf(al + bl) | ((unsigned int)f2bf(ah + bh) << 16);
}

// async global->LDS, 16B per lane; LDS dest = wave-uniform base + lane*16
#define GLL16(g, l) __builtin_amdgcn_global_load_lds( \
    (const __attribute__((address_space(1))) unsigned int*)(uintptr_t)(g), \
    (__attribute__((address_space(3))) unsigned int*)(uintptr_t)(l), 16, 0, 0)

// m204 bijective XCD swizzle
__device__ __forceinline__ int xcd_swz(int bid, int nblk) {
    int q = nblk >> 3, r = nblk & 7;
    int xcd = bid & 7, idx = bid >> 3;
    int base = (xcd < r) ? xcd * (q + 1) : r * (q + 1) + (xcd - r) * q;
    return base + idx;
}

// ---------------- out = -x (fallback path only) ----------------
__global__ void k_init_out(const float* __restrict__ x, float* __restrict__ out) {
    int i = blockIdx.x * blockDim.x + threadIdx.x;
    const float4* xv = (const float4*)x;
    float4* ov = (float4*)out;
    float4 v = xv[i];
    ov[i] = make_float4(-v.x, -v.y, -v.z, -v.w);
}

// ---------------- gate layer1 (R7-v3 loop + coalesced LDS-transpose epilogue) ----------------
__global__ __launch_bounds__(256) void k_gate1(
        const float* __restrict__ x, const float* __restrict__ Wg1,
        float* __restrict__ gs_part) {
    __shared__ float xs[32][68];     // [k][m], pad 68
    __shared__ float wt[32][200];    // [k][n], pad 200 (also epilogue scratch)
    int bm = blockIdx.x % 197, kh = blockIdx.x / 197;
    int m0 = bm * 64, k0 = kh * (F_ / KH_);
    int tid = threadIdx.x, lane = tid & 63, wid = tid >> 6;
    int mg = lane & 15;
    int ng = (lane >> 4) + 4 * wid;
    f32x4 acc[4][3] = {};

    int xr = tid >> 3, xc = tid & 7;
    float4 xreg0, xreg1;
    float4 wreg[6];

    auto loadRegs = [&](int t) {
        int kb = k0 + t * 32;
        xreg0 = *(const float4*)(x + (size_t)(m0 + xr) * F_ + kb + xc * 4);
        xreg1 = *(const float4*)(x + (size_t)(m0 + xr + 32) * F_ + kb + xc * 4);
        #pragma unroll
        for (int i = 0; i < 6; ++i) {
            int idx = tid + i * 256;
            int kr = idx / 48, nc = idx % 48;
            wreg[i] = *(const float4*)(Wg1 + (size_t)(kb + kr) * G_ + nc * 4);
        }
    };
    auto writeLDS = [&]() {
        xs[xc * 4 + 0][xr] = xreg0.x;  xs[xc * 4 + 1][xr] = xreg0.y;
        xs[xc * 4 + 2][xr] = xreg0.z;  xs[xc * 4 + 3][xr] = xreg0.w;
        xs[xc * 4 + 0][xr + 32] = xreg1.x;  xs[xc * 4 + 1][xr + 32] = xreg1.y;
        xs[xc * 4 + 2][xr + 32] = xreg1.z;  xs[xc * 4 + 3][xr + 32] = xreg1.w;
        #pragma unroll
        for (int i = 0; i < 6; ++i) {
            int idx = tid + i * 256;
            int kr = idx / 48, nc = idx % 48;
            *(float4*)&wt[kr][nc * 4] = wreg[i];
        }
    };

    loadRegs(0);
    for (int t = 0; t < 6; ++t) {
        __syncthreads();
        writeLDS();
        __syncthreads();
        if (t < 5) loadRegs(t + 1);
        #pragma unroll
        for (int k = 0; k < 32; ++k) {
            float4 av = *(const float4*)&xs[k][mg * 4];
            f32x4 b0 = *(const f32x4*)&wt[k][ng * 12];
            f32x4 b1 = *(const f32x4*)&wt[k][ng * 12 + 4];
            f32x4 b2 = *(const f32x4*)&wt[k][ng * 12 + 8];
            float am[4] = {av.x, av.y, av.z, av.w};
            #pragma unroll
            for (int mi = 0; mi < 4; ++mi) {
                acc[mi][0] += b0 * am[mi];
                acc[mi][1] += b1 * am[mi];
                acc[mi][2] += b2 * am[mi];
            }
        }
    }
    // coalesced epilogue: 2 chunks of 32 rows via LDS scratch (wt is dead)
    float* scratch = &wt[0][0];
    #pragma unroll
    for (int ch = 0; ch < 2; ++ch) {
        __syncthreads();
        if ((mg >> 3) == ch) {
            int lr = (mg & 7) * 4;
            #pragma unroll
            for (int mi = 0; mi < 4; ++mi) {
                float* rp = scratch + (size_t)(lr + mi) * 196 + ng * 12;
                *(f32x4*)(rp + 0) = acc[mi][0];
                *(f32x4*)(rp + 4) = acc[mi][1];
                *(f32x4*)(rp + 8) = acc[mi][2];
            }
        }
        __syncthreads();
        float* gp = gs_part + (size_t)kh * TB_ * G_ + (size_t)(m0 + ch * 32) * G_;
        #pragma unroll
        for (int i = 0; i < 6; ++i) {
            int idx = tid + i * 256;
            int r = idx / 48, c4 = idx % 48;
            *(float4*)(gp + (size_t)r * G_ + c4 * 4) =
                *(const float4*)(scratch + (size_t)r * 196 + c4 * 4);
        }
    }
}

// ---------------- gate layer2: reduce 4 partials + bias + relu -> logits -> softmax -> top2 ----------------
__global__ __launch_bounds__(256) void k_gate2(
        const float* __restrict__ gs_part, const float* __restrict__ bg1,
        const float* __restrict__ Wg2, const float* __restrict__ bg2,
        float* __restrict__ cw, int* __restrict__ ecnt) {
    __shared__ float gsh[32][200];
    __shared__ float wg2s[G_ * N_];
    __shared__ float lg[32][8];
    int tid = threadIdx.x;
    int id0 = blockIdx.x * 32;

    for (int i = tid; i < 32 * 48; i += 256) {
        int r = i / 48, c4 = i % 48;
        const float* p0 = gs_part + (size_t)(id0 + r) * G_ + c4 * 4;
        float4 g = *(const float4*)(bg1 + c4 * 4);
        float4 v = g;
        #pragma unroll
        for (int p = 0; p < KH_; ++p) {
            float4 a = *(const float4*)(p0 + (size_t)p * TB_ * G_);
            v.x += a.x; v.y += a.y; v.z += a.z; v.w += a.w;
        }
        v.x = fmaxf(v.x, 0.f); v.y = fmaxf(v.y, 0.f);
        v.z = fmaxf(v.z, 0.f); v.w = fmaxf(v.w, 0.f);
        ((float4*)&gsh[r][0])[c4] = v;
    }
    for (int i = tid; i < G_ * N_; i += 256) wg2s[i] = Wg2[i];
    __syncthreads();

    int tk = tid >> 3, n = tid & 7;
    float a = bg2[n];
    for (int k = 0; k < G_; ++k) a += gsh[tk][k] * wg2s[k * N_ + n];
    lg[tk][n] = a;
    __syncthreads();

    if (tid < 32) {
        int tk2 = tid;
        float p[8];
        float m = lg[tk2][0];
        #pragma unroll
        for (int nn = 1; nn < 8; ++nn) m = fmaxf(m, lg[tk2][nn]);
        float s = 0.f;
        #pragma unroll
        for (int nn = 0; nn < 8; ++nn) { p[nn] = expf(lg[tk2][nn] - m); s += p[nn]; }
        float inv = 1.f / s;
        #pragma unroll
        for (int nn = 0; nn < 8; ++nn) p[nn] *= inv;
        int i1 = 0; float v1 = p[0];
        #pragma unroll
        for (int nn = 1; nn < 8; ++nn) if (p[nn] > v1) { v1 = p[nn]; i1 = nn; }
        int i2 = -1; float v2 = -1.f;
        #pragma unroll
        for (int nn = 0; nn < 8; ++nn) if (nn != i1 && p[nn] > v2) { v2 = p[nn]; i2 = nn; }
        int id = id0 + tk2;
        int t = id / B_, b = id % B_;
        ecnt[id] = 0;
        #pragma unroll
        for (int nn = 0; nn < 8; ++nn) {
            float v = (nn == i1 || nn == i2) ? p[nn] : 0.f;
            cw[((size_t)(b * N_ + nn)) * T_ + t] = v;
        }
    }
}

// ---------------- gate (fallback path only) ----------------
__global__ __launch_bounds__(256) void k_gate(
        const float* __restrict__ x, const float* __restrict__ Wg1,
        const float* __restrict__ bg1, const float* __restrict__ Wg2,
        const float* __restrict__ bg2, float* __restrict__ cw,
        int* __restrict__ ecnt) {
    __shared__ float xsh[8][F_];
    __shared__ float gsl[8][G_];
    __shared__ float lg[8][N_];
    int tid = threadIdx.x;
    int id0 = blockIdx.x * 8;

    int gid = blockIdx.x * 256 + tid;
    if (gid < TB_ && ecnt) ecnt[gid] = 0;

    const float4* xv = (const float4*)(x + (size_t)id0 * F_);
    float4* xshv = (float4*)&xsh[0][0];
    for (int idx = tid; idx < 8 * (F_/4); idx += 256) xshv[idx] = xv[idx];
    __syncthreads();

    if (tid < G_) {
        float acc[8];
        float bb = bg1[tid];
        #pragma unroll
        for (int tk = 0; tk < 8; ++tk) acc[tk] = bb;
        for (int k = 0; k < F_; ++k) {
            float w = Wg1[k * G_ + tid];
            #pragma unroll
            for (int tk = 0; tk < 8; ++tk) acc[tk] += xsh[tk][k] * w;
        }
        #pragma unroll
        for (int tk = 0; tk < 8; ++tk) gsl[tk][tid] = fmaxf(acc[tk], 0.f);
    }
    __syncthreads();

    if (tid < 64) {
        int tk = tid >> 3, n = tid & 7;
        float acc = bg2[n];
        for (int k = 0; k < G_; ++k) acc += gsl[tk][k] * Wg2[k * N_ + n];
        lg[tk][n] = acc;
    }
    __syncthreads();

    if (tid < 8) {
        int tk = tid;
        float p[8];
        float m = lg[tk][0];
        #pragma unroll
        for (int n = 1; n < 8; ++n) m = fmaxf(m, lg[tk][n]);
        float s = 0.f;
        #pragma unroll
        for (int n = 0; n < 8; ++n) { p[n] = expf(lg[tk][n] - m); s += p[n]; }
        float inv = 1.f / s;
        #pragma unroll
        for (int n = 0; n < 8; ++n) p[n] *= inv;
        int i1 = 0; float v1 = p[0];
        #pragma unroll
        for (int n = 1; n < 8; ++n) if (p[n] > v1) { v1 = p[n]; i1 = n; }
        int i2 = -1; float v2 = -1.f;
        #pragma unroll
        for (int n = 0; n < 8; ++n) if (n != i1 && p[n] > v2) { v2 = p[n]; i2 = n; }
        int id = id0 + tk;
        int t = id / B_, b = id % B_;
        #pragma unroll
        for (int n = 0; n < 8; ++n) {
            float v = (n == i1 || n == i2) ? p[n] : 0.f;
            cw[((size_t)(b * N_ + n)) * T_ + t] = v;
        }
    }
}

// ---------------- capacity: exact top-CAP rank per (b,n); builds inverse map ----------------
__global__ __launch_bounds__(256) void k_capacity(
        const float* __restrict__ cw, int* __restrict__ toks,
        float* __restrict__ wts, int* __restrict__ counts,
        int* __restrict__ ecnt, int* __restrict__ erow) {
    __shared__ float v[T_];
    __shared__ int keep[T_];
    int tid = threadIdx.x;
    int bn = blockIdx.x;
    int b = bn >> 3, n = bn & 7;
    if (tid < T_) v[tid] = cw[(size_t)bn * T_ + tid];
    __syncthreads();
    int kp = 0; float my = 0.f;
    if (tid < T_) {
        my = v[tid];
        int rank = 0;
        for (int t2 = 0; t2 < T_; ++t2) {
            float vt = v[t2];
            rank += (vt > my) || (vt == my && t2 < tid);
        }
        kp = (rank < CAP_) && (my > 0.f);
    }
    if (tid < T_) keep[tid] = kp;
    __syncthreads();
    if (tid < T_ && kp) {
        int slot = 0;
        for (int t2 = 0; t2 < T_; ++t2) slot += (t2 < tid) ? keep[t2] : 0;
        toks[bn * CAP_ + slot] = tid;
        wts[bn * CAP_ + slot] = my;
        if (ecnt) {
            int orow = tid * B_ + b;
            int pos = atomicAdd(&ecnt[orow], 1);
            erow[orow * 2 + pos] = n * ME_ + b * CAP_ + slot;
        }
    }
    if (tid == 0) {
        int tot = 0;
        for (int t2 = 0; t2 < T_; ++t2) tot += keep[t2];
        counts[bn] = tot;
    }
}

// ---------------- repack W [E][K][J] fp32 -> WT [E][J][K] bf16, pre-swizzled ----------------
__global__ __launch_bounds__(256) void k_repack(
        const float* __restrict__ W, unsigned short* __restrict__ WT, int K, int J) {
    __shared__ float tile[64][65];
    int bid = blockIdx.x;
    int nk = K >> 6, nj = J >> 6;
    int kt = bid % nk; bid /= nk;
    int jt = bid % nj; int e = bid / nj;
    int k0 = kt * 64, j0 = jt * 64;
    int tid = threadIdx.x;
    int jr = (tid & 15) << 2;
    int kr = tid >> 4;
    const float* src = W + ((size_t)e * K + k0) * J + j0;
    #pragma unroll
    for (int i = 0; i < 4; ++i) {
        float4 v = *(const float4*)(src + (size_t)(kr + 16 * i) * J + jr);
        *(float4*)&tile[kr + 16 * i][jr] = v;
    }
    __syncthreads();
    int c = tid & 7;
    int jrow = tid >> 3;
    #pragma unroll
    for (int i = 0; i < 2; ++i) {
        int j = jrow + 32 * i;
        float f[8];
        #pragma unroll
        for (int s = 0; s < 8; ++s) f[s] = tile[c * 8 + s][j];
        uint4 u;
        u.x = f2bf(f[0]) | ((unsigned)f2bf(f[1]) << 16);
        u.y = f2bf(f[2]) | ((unsigned)f2bf(f[3]) << 16);
        u.z = f2bf(f[4]) | ((unsigned)f2bf(f[5]) << 16);
        u.w = f2bf(f[6]) | ((unsigned)f2bf(f[7]) << 16);
        int jg = j0 + j;
        char* drow = (char*)WT + ((size_t)e * J + jg) * (size_t)K * 2 + (size_t)(k0 >> 6) * 128;
        *(uint4*)(drow + ((c << 4) ^ ((jg & 7) << 4))) = u;
    }
}

// ---------------- gather x rows -> Xg [MT_][768] bf16, pre-swizzled, zero-padded ----------------
__global__ __launch_bounds__(256) void k_gather(
        const float* __restrict__ x, const int* __restrict__ toks,
        const int* __restrict__ counts, unsigned short* __restrict__ Xg) {
    int gi = blockIdx.x * 256 + threadIdx.x;
    int R = gi / 96, c = gi - R * 96;
    int e = R / ME_, re = R - e * ME_;
    uint4 val = make_uint4(0u, 0u, 0u, 0u);
    if (re < MR_) {
        int g = re / CAP_, slot = re - g * CAP_;
        int bn = g * N_ + e;
        if (slot < counts[bn]) {
            int t = toks[bn * CAP_ + slot];
            const float* xp = x + ((size_t)t * B_ + g) * F_ + c * 8;
            float4 v0 = *(const float4*)xp;
            float4 v1 = *(const float4*)(xp + 4);
            val.x = f2bf(v0.x) | ((unsigned)f2bf(v0.y) << 16);
            val.y = f2bf(v0.z) | ((unsigned)f2bf(v0.w) << 16);
            val.z = f2bf(v1.x) | ((unsigned)f2bf(v1.y) << 16);
            val.w = f2bf(v1.z) | ((unsigned)f2bf(v1.w) << 16);
        }
    }
    int w = (c * 16) & 127;
    char* dst = (char*)Xg + (size_t)R * 1536 + (c >> 3) * 128 + (w ^ ((R & 7) << 4));
    *(uint4*)dst = val;
}

// ---------------- GEMM1 (unified): Hg cols = relu(W1T . Xg^T + b1) ----------------
__global__ __launch_bounds__(256) void k_gemm1(
        const unsigned short* __restrict__ W1T, const unsigned short* __restrict__ Xg,
        const float* __restrict__ b1, unsigned short* __restrict__ Hg,
        int njt, int jofs, int hstrideB, int nblk) {
    __shared__ char ldsA[2][16384];
    __shared__ char ldsB[2][16384];
    int swzb = xcd_swz(blockIdx.x, nblk);
    int per_e = 25 * njt;
    int e = swzb / per_e;
    int rem = swzb - e * per_e;
    int mt = rem / njt, jtl = rem % njt;
    int jt = jofs + jtl;
    int tid = threadIdx.x, lane = tid & 63, wid = tid >> 6;
    int lr8 = lane >> 3, sl = (lane & 7) << 4;
    const char* Ab = (const char*)W1T + ((size_t)e * H_ + (size_t)jt * 128) * (F_ * 2);
    const char* Bb = (const char*)Xg + ((size_t)e * ME_ + (size_t)mt * 128) * (F_ * 2);
    f32x4 acc[4][4] = {};
    int swz = (lane & 7) << 4;
    int q16 = (lane >> 4) << 4;

    auto stage = [&](int buf, int it) {
        int kb = it << 7;
        #pragma unroll
        for (int i = 0; i < 4; ++i) {
            int lr = wid * 32 + i * 8 + lr8;
            GLL16(Ab + (size_t)lr * 1536 + kb + sl, ldsA[buf] + (wid * 32 + i * 8) * 128);
            GLL16(Bb + (size_t)lr * 1536 + kb + sl, ldsB[buf] + (wid * 32 + i * 8) * 128);
        }
    };

    stage(0, 0);
    __syncthreads();
    int cur = 0;
    for (int it = 0; it < 12; ++it) {
        if (it < 11) stage(cur ^ 1, it + 1);
        const char* la = ldsA[cur] + ((wid & 1) * 64) * 128;
        const char* lb = ldsB[cur] + ((wid >> 1) * 64) * 128;
        #pragma unroll
        for (int ks = 0; ks < 2; ++ks) {
            bf16x8 af[4], bfr[4];
            int kk = (ks * 64 + q16) ^ swz;
            #pragma unroll
            for (int t = 0; t < 4; ++t) {
                int ro = (16 * t + (lane & 15)) * 128;
                af[t]  = *(const bf16x8*)(la + ro + kk);
                bfr[t] = *(const bf16x8*)(lb + ro + kk);
            }
            #pragma unroll
            for (int ti = 0; ti < 4; ++ti)
                #pragma unroll
                for (int tm = 0; tm < 4; ++tm)
                    acc[ti][tm] = __builtin_amdgcn_mfma_f32_16x16x32_bf16(af[ti], bfr[tm], acc[ti][tm], 0, 0, 0);
        }
        __syncthreads();
        cur ^= 1;
    }
    char* tile = &ldsA[0][0];
    int jl0 = (wid & 1) * 64;
    int ml0 = (wid >> 1) * 64;
    const float* b1p = b1 + (size_t)e * H_ + (size_t)jt * 128;
    #pragma unroll
    for (int tj = 0; tj < 4; ++tj) {
        int jc = jl0 + 16 * tj + ((lane >> 4) << 2);
        float bb0 = b1p[jc], bb1 = b1p[jc + 1], bb2 = b1p[jc + 2], bb3 = b1p[jc + 3];
        #pragma unroll
        for (int tm = 0; tm < 4; ++tm) {
            int m = ml0 + 16 * tm + (lane & 15);
            f32x4 a = acc[tj][tm];
            unsigned int u0 = f2bf(fmaxf(a[0] + bb0, 0.f)) | ((unsigned)f2bf(fmaxf(a[1] + bb1, 0.f)) << 16);
            unsigned int u1 = f2bf(fmaxf(a[2] + bb2, 0.f)) | ((unsigned)f2bf(fmaxf(a[3] + bb3, 0.f)) << 16);
            int bcol = jc * 2;
            int w = bcol & 127;
            *(uint2*)(tile + m * 256 + (bcol & ~127) + (w ^ ((m & 7) << 4))) = make_uint2(u0, u1);
        }
    }
    __syncthreads();
    char* Hrow = (char*)Hg + ((size_t)e * ME_ + (size_t)mt * 128) * hstrideB + (size_t)jtl * 256;
    #pragma unroll
    for (int i = 0; i < 8; ++i) {
        int idx = tid + i * 256;
        int r = idx >> 4, c = (idx & 15) << 4;
        *(uint4*)(Hrow + (size_t)r * hstrideB + c) = *(const uint4*)(tile + r * 256 + c);
    }
}

// ---------------- GEMM2 (unified): Og (+)= fw * (W2T[K-slice] . Hg^T) (+fw*b2 when kofsB==0) ----------------
__global__ __launch_bounds__(256) void k_gemm2(
        const unsigned short* __restrict__ W2T, const unsigned short* __restrict__ Hg,
        const float* __restrict__ b2, const float* __restrict__ wts,
        const int* __restrict__ counts, unsigned short* __restrict__ Og,
        int kiters, int kofsB, int bstrideB, int nblk) {
    __shared__ char ldsA[2][16384];
    __shared__ char ldsB[2][16384];
    int swzb = xcd_swz(blockIdx.x, nblk);
    int e = swzb / 150;
    int rem = swzb - e * 150;
    int mt = rem / 6, ft = rem % 6;
    int tid = threadIdx.x, lane = tid & 63, wid = tid >> 6;
    int lr8 = lane >> 3, sl = (lane & 7) << 4;
    const char* Ab = (const char*)W2T + ((size_t)e * F_ + (size_t)ft * 128) * (H_ * 2) + kofsB;
    const char* Bb = (const char*)Hg + ((size_t)e * ME_ + (size_t)mt * 128) * bstrideB;
    f32x4 acc[4][4] = {};
    int swz = (lane & 7) << 4;
    int q16 = (lane >> 4) << 4;

    auto stage = [&](int buf, int it) {
        int kb = it << 7;
        #pragma unroll
        for (int i = 0; i < 4; ++i) {
            int lr = wid * 32 + i * 8 + lr8;
            GLL16(Ab + (size_t)lr * 6144 + kb + sl, ldsA[buf] + (wid * 32 + i * 8) * 128);
            GLL16(Bb + (size_t)lr * bstrideB + kb + sl, ldsB[buf] + (wid * 32 + i * 8) * 128);
        }
    };

    stage(0, 0);
    __syncthreads();
    int cur = 0;
    for (int it = 0; it < kiters; ++it) {
        if (it < kiters - 1) stage(cur ^ 1, it + 1);
        const char* la = ldsA[cur] + ((wid & 1) * 64) * 128;
        const char* lb = ldsB[cur] + ((wid >> 1) * 64) * 128;
        #pragma unroll
        for (int ks = 0; ks < 2; ++ks) {
            bf16x8 af[4], bfr[4];
            int kk = (ks * 64 + q16) ^ swz;
            #pragma unroll
            for (int t = 0; t < 4; ++t) {
                int ro = (16 * t + (lane & 15)) * 128;
                af[t]  = *(const bf16x8*)(la + ro + kk);
                bfr[t] = *(const bf16x8*)(lb + ro + kk);
            }
            #pragma unroll
            for (int ti = 0; ti < 4; ++ti)
                #pragma unroll
                for (int tm = 0; tm < 4; ++tm)
                    acc[ti][tm] = __builtin_amdgcn_mfma_f32_16x16x32_bf16(af[ti], bfr[tm], acc[ti][tm], 0, 0, 0);
        }
        __syncthreads();
        cur ^= 1;
    }
    char* tile = &ldsA[0][0];
    int fl0 = (wid & 1) * 64;
    int ml0 = (wid >> 1) * 64;
    const float* b2p = b2 + (size_t)e * F_ + (size_t)ft * 128;
    float fwv[4];
    #pragma unroll
    for (int tm = 0; tm < 4; ++tm) {
        int mloc = ml0 + 16 * tm + (lane & 15);
        int re = mt * 128 + mloc;
        float fw = 0.f;
        if (re < MR_) {
            int g = re / CAP_;
            int slot = re - g * CAP_;
            int bn = g * N_ + e;
            if (slot < counts[bn]) fw = wts[bn * CAP_ + slot];
        }
        fwv[tm] = fw;
    }
    int p0 = (kofsB == 0);
    #pragma unroll
    for (int tf = 0; tf < 4; ++tf) {
        int fc = fl0 + 16 * tf + ((lane >> 4) << 2);
        float c0 = 0.f, c1 = 0.f, c2 = 0.f, c3 = 0.f;
        if (p0) { c0 = b2p[fc]; c1 = b2p[fc + 1]; c2 = b2p[fc + 2]; c3 = b2p[fc + 3]; }
        #pragma unroll
        for (int tm = 0; tm < 4; ++tm) {
            int mloc = ml0 + 16 * tm + (lane & 15);
            f32x4 a = acc[tf][tm];
            float fw = fwv[tm];
            unsigned int u0 = f2bf(fw * (a[0] + c0)) | ((unsigned)f2bf(fw * (a[1] + c1)) << 16);
            unsigned int u1 = f2bf(fw * (a[2] + c2)) | ((unsigned)f2bf(fw * (a[3] + c3)) << 16);
            int bcol = fc * 2;
            int w = bcol & 127;
            *(uint2*)(tile + mloc * 256 + (bcol & ~127) + (w ^ ((mloc & 7) << 4))) = make_uint2(u0, u1);
        }
    }
    __syncthreads();
    char* Orow = (char*)Og + ((size_t)e * ME_ + (size_t)mt * 128) * (F_ * 2) + (size_t)ft * 256;
    if (p0) {
        #pragma unroll
        for (int i = 0; i < 8; ++i) {
            int idx = tid + i * 256;
            int r = idx >> 4, c = (idx & 15) << 4;
            const char* src = tile + r * 256 + (c & ~127) + ((c & 127) ^ ((r & 7) << 4));
            *(uint4*)(Orow + (size_t)r * (F_ * 2) + c) = *(const uint4*)src;
        }
    } else {
        #pragma unroll
        for (int i = 0; i < 8; ++i) {
            int idx = tid + i * 256;
            int r = idx >> 4, c = (idx & 15) << 4;
            const char* src = tile + r * 256 + (c & ~127) + ((c & 127) ^ ((r & 7) << 4));
            uint4 nw = *(const uint4*)src;
            uint4* dst = (uint4*)(Orow + (size_t)r * (F_ * 2) + c);
            uint4 old = *dst;
            uint4 res;
            res.x = add2bf(old.x, nw.x);
            res.y = add2bf(old.y, nw.y);
            res.z = add2bf(old.z, nw.z);
            res.w = add2bf(old.w, nw.w);
            *dst = res;
        }
    }
}

// ---------------- combine: out[t,b,:] = sum(og entries) - x ----------------
__global__ __launch_bounds__(256) void k_combine(
        const float* __restrict__ x, const unsigned short* __restrict__ Og,
        const int* __restrict__ ecnt, const int* __restrict__ erow,
        float* __restrict__ out) {
    int idx = blockIdx.x * 256 + threadIdx.x;
    int row = idx / 192, c4 = idx - row * 192;
    float4 s = make_float4(0.f, 0.f, 0.f, 0.f);
    int c = ecnt[row];
    if (c > 0) {
        ushort4 u = *(const ushort4*)(Og + (size_t)erow[row * 2] * F_ + c4 * 4);
        s.x += bf2f(u.x); s.y += bf2f(u.y); s.z += bf2f(u.z); s.w += bf2f(u.w);
    }
    if (c > 1) {
        ushort4 u = *(const ushort4*)(Og + (size_t)erow[row * 2 + 1] * F_ + c4 * 4);
        s.x += bf2f(u.x); s.y += bf2f(u.y); s.z += bf2f(u.z); s.w += bf2f(u.w);
    }
    float4 xv = ((const float4*)x)[idx];
    ((float4*)out)[idx] = make_float4(s.x - xv.x, s.y - xv.y, s.z - xv.z, s.w - xv.w);
}

// ================= round-1 fallback kernels (tiny ws only) =================
__global__ __launch_bounds__(HCF_) void k_fc1(
        const float* __restrict__ x, const float* __restrict__ W1,
        const float* __restrict__ b1, const int* __restrict__ toks,
        const int* __restrict__ counts, __hip_bfloat16* __restrict__ h, int pass) {
    __shared__ float xs[25][F_];
    int tid = threadIdx.x;
    int bn = blockIdx.x >> 1;
    int half = blockIdx.x & 1;
    int r0 = half * 25;
    int b = bn >> 3, n = bn & 7;
    int c = counts[bn];
    for (int idx = tid; idx < 25 * (F_/4); idx += HCF_) {
        int r = idx / (F_/4), k4 = idx % (F_/4);
        int gr = r0 + r;
        float4 val = make_float4(0.f, 0.f, 0.f, 0.f);
        if (gr < c) {
            int t = toks[bn * CAP_ + gr];
            val = ((const float4*)(x + ((size_t)(t * B_ + b)) * F_))[k4];
        }
        ((float4*)&xs[r][0])[k4] = val;
    }
    __syncthreads();
    int j = pass * HCF_ + tid;
    const float* w1p = W1 + (size_t)n * F_ * H_ + j;
    float bias = b1[n * H_ + j];
    float acc[25];
    #pragma unroll
    for (int r = 0; r < 25; ++r) acc[r] = bias;
    const float4* xsv = (const float4*)&xs[0][0];
    for (int k4 = 0; k4 < F_/4; ++k4) {
        float w0 = w1p[(size_t)(4*k4+0) * H_];
        float w1v = w1p[(size_t)(4*k4+1) * H_];
        float w2v = w1p[(size_t)(4*k4+2) * H_];
        float w3v = w1p[(size_t)(4*k4+3) * H_];
        #pragma unroll
        for (int r = 0; r < 25; ++r) {
            float4 xv = xsv[r * (F_/4) + k4];
            acc[r] += xv.x*w0 + xv.y*w1v + xv.z*w2v + xv.w*w3v;
        }
    }
    __hip_bfloat16* hp = h + ((size_t)bn * CAP_ + r0) * HCF_ + tid;
    #pragma unroll
    for (int r = 0; r < 25; ++r) {
        int gr = r0 + r;
        if (gr < CAP_) hp[(size_t)r * HCF_] = __float2bfloat16(fmaxf(acc[r], 0.f));
    }
}

__global__ __launch_bounds__(768) void k_fc2(
        const float* __restrict__ W2, const float* __restrict__ b2,
        const int* __restrict__ toks, const float* __restrict__ wts,
        const int* __restrict__ counts, const __hip_bfloat16* __restrict__ h,
        float* __restrict__ out, int pass) {
    __shared__ float hs[CAP_][HCF_];
    int tid = threadIdx.x;
    int bn = blockIdx.x;
    int c = counts[bn];
    if (c == 0) return;
    int b = bn >> 3, n = bn & 7;
    const ushort4* hv = (const ushort4*)(h + (size_t)bn * CAP_ * HCF_);
    for (int idx = tid; idx < CAP_ * (HCF_/4); idx += 768) {
        ushort4 u = hv[idx];
        float4 fv;
        fv.x = __bfloat162float(*(const __hip_bfloat16*)&u.x);
        fv.y = __bfloat162float(*(const __hip_bfloat16*)&u.y);
        fv.z = __bfloat162float(*(const __hip_bfloat16*)&u.z);
        fv.w = __bfloat162float(*(const __hip_bfloat16*)&u.w);
        ((float4*)&hs[0][0])[idx] = fv;
    }
    __syncthreads();
    int f = tid;
    const float* w2p = W2 + (size_t)n * H_ * F_ + (size_t)(pass * HCF_) * F_ + f;
    float acc[CAP_];
    #pragma unroll
    for (int r = 0; r < CAP_; ++r) acc[r] = 0.f;
    for (int j4 = 0; j4 < HCF_/4; ++j4) {
        float w0 = w2p[(size_t)(4*j4+0) * F_];
        float w1v = w2p[(size_t)(4*j4+1) * F_];
        float w2v = w2p[(size_t)(4*j4+2) * F_];
        float w3v = w2p[(size_t)(4*j4+3) * F_];
        #pragma unroll
        for (int r = 0; r < CAP_; ++r) {
            float4 hh = ((const float4*)&hs[r][0])[j4];
            acc[r] += hh.x*w0 + hh.y*w1v + hh.z*w2v + hh.w*w3v;
        }
    }
    float bias = (pass == 0) ? b2[n * F_ + f] : 0.f;
    #pragma unroll
    for (int r = 0; r < CAP_; ++r) {
        if (r < c) {
            int t = toks[bn * CAP_ + r];
            float fw = wts[bn * CAP_ + r];
            atomicAdd(&out[((size_t)(t * B_ + b)) * F_ + f], fw * (acc[r] + bias));
        }
    }
}

extern "C" void kernel_launch(void* const* d_in, const int* in_sizes, int n_in,
                              void* d_out, int out_size, void* d_ws, size_t ws_size,
                              hipStream_t stream) {
    const float* x   = (const float*)d_in[0];
    const float* Wg1 = (const float*)d_in[1];
    const float* bg1 = (const float*)d_in[2];
    const float* Wg2 = (const float*)d_in[3];
    const float* bg2 = (const float*)d_in[4];
    const float* W1  = (const float*)d_in[5];
    const float* b1  = (const float*)d_in[6];
    const float* W2  = (const float*)d_in[7];
    const float* b2  = (const float*)d_in[8];
    float* out = (float*)d_out;

    // ws layout
    size_t oW1T  = 0;
    size_t oW2T  = oW1T + (size_t)N_ * H_ * F_ * 2;
    size_t oXg   = oW2T + (size_t)N_ * H_ * F_ * 2;
    size_t oCw   = oXg  + (size_t)MT_ * F_ * 2;
    size_t oWts  = oCw  + (size_t)NBN_ * T_ * 4;
    size_t oTok  = oWts + (size_t)NBN_ * CAP_ * 4;
    size_t oCnt  = oTok + (size_t)NBN_ * CAP_ * 4;
    size_t oEcnt = oCnt + (size_t)NBN_ * 4;
    size_t oErow = oEcnt + (size_t)TB_ * 4;
    size_t oOg   = oErow + (size_t)TB_ * 8;
    size_t oHg   = oOg  + (size_t)MT_ * F_ * 2;
    size_t gsBytes = (size_t)KH_ * TB_ * G_ * 4;     // 38.7 MB
    size_t needB  = oHg + (size_t)MT_ * HP_ * 2;     // ~194 MB (H-pass tier)
    size_t needA  = oHg + (size_t)MT_ * H_ * 2;      // ~312 MB (full-Hg tier)
    size_t needB2 = needB + gsBytes;                 // tier B + dedicated gs
    size_t needA2 = needA + gsBytes;                 // tier A + dedicated gs

    if (ws_size >= needB) {
        unsigned short* W1T = (unsigned short*)((char*)d_ws + oW1T);
        unsigned short* W2T = (unsigned short*)((char*)d_ws + oW2T);
        unsigned short* Xg  = (unsigned short*)((char*)d_ws + oXg);
        unsigned short* Og  = (unsigned short*)((char*)d_ws + oOg);
        unsigned short* Hg  = (unsigned short*)((char*)d_ws + oHg);
        float* cw   = (float*)((char*)d_ws + oCw);
        float* wts  = (float*)((char*)d_ws + oWts);
        int* toks   = (int*)((char*)d_ws + oTok);
        int* counts = (int*)((char*)d_ws + oCnt);
        int* ecnt   = (int*)((char*)d_ws + oEcnt);
        int* erow   = (int*)((char*)d_ws + oErow);

        int tierA = (ws_size >= needA);
        // gs_part: dedicated region (never dirtied by other kernels) if ws allows; else alias Og
        float* gs_part;
        if (tierA)       gs_part = (ws_size >= needA2) ? (float*)((char*)d_ws + needA) : (float*)((char*)d_ws + oOg);
        else             gs_part = (ws_size >= needB2) ? (float*)((char*)d_ws + needB) : (float*)((char*)d_ws + oOg);

        k_gate1<<<197 * KH_, 256, 0, stream>>>(x, Wg1, gs_part);
        k_gate2<<<TB_ / 32, 256, 0, stream>>>(gs_part, bg1, Wg2, bg2, cw, ecnt);
        k_capacity<<<NBN_, 256, 0, stream>>>(cw, toks, wts, counts, ecnt, erow);
        k_repack<<<N_ * (F_/64) * (H_/64), 256, 0, stream>>>(W1, W1T, F_, H_);
        k_repack<<<N_ * (H_/64) * (F_/64), 256, 0, stream>>>(W2, W2T, H_, F_);
        k_gather<<<(MT_ * 96) / 256, 256, 0, stream>>>(x, toks, counts, Xg);
        if (tierA) {
            k_gemm1<<<4800, 256, 0, stream>>>(W1T, Xg, b1, Hg, 24, 0, H_ * 2, 4800);
            k_gemm2<<<1200, 256, 0, stream>>>(W2T, Hg, b2, wts, counts, Og, 48, 0, H_ * 2, 1200);
        } else {
            for (int p = 0; p < 4; ++p) {
                k_gemm1<<<1200, 256, 0, stream>>>(W1T, Xg, b1, Hg, 6, p * 6, HP_ * 2, 1200);
                k_gemm2<<<1200, 256, 0, stream>>>(W2T, Hg, b2, wts, counts, Og, 12, p * HP_ * 2, HP_ * 2, 1200);
            }
        }
        k_combine<<<(TB_ * 192) / 256, 256, 0, stream>>>(x, Og, ecnt, erow, out);
    } else {
        // round-1 fallback (~20 MB ws)
        __hip_bfloat16* h = (__hip_bfloat16*)d_ws;
        float* cw  = (float*)((char*)d_ws + (size_t)NBN_ * CAP_ * HCF_ * 2);
        float* wts = cw + (size_t)NBN_ * T_;
        int* toks  = (int*)(wts + NBN_ * CAP_);
        int* counts = toks + NBN_ * CAP_;
        k_init_out<<<(TB_ * F_) / 1024, 256, 0, stream>>>(x, out);
        k_gate<<<TB_ / 8, 256, 0, stream>>>(x, Wg1, bg1, Wg2, bg2, cw, nullptr);
        k_capacity<<<NBN_, 256, 0, stream>>>(cw, toks, wts, counts, nullptr, nullptr);
        for (int p = 0; p < NPF_; ++p) {
            k_fc1<<<NBN_ * 2, HCF_, 0, stream>>>(x, W1, b1, toks, counts, h, p);
            k_fc2<<<NBN_, 768, 0, stream>>>(W2, b2, toks, wts, counts, h, out, p);
        }
    }
}

// Round 16
// 495.776 us; speedup vs baseline: 1.0443x; 1.0443x over previous
//
#include <hip/hip_runtime.h>
#include <hip/hip_bf16.h>
#include <math.h>
#include <stdint.h>

#define T_ 197
#define B_ 64
#define F_ 768
#define N_ 8
#define CAP_ 49
#define H_ 3072
#define G_ 192
#define TB_ (T_*B_)       // 12608
#define NBN_ (B_*N_)      // 512
#define ME_ 3200          // padded rows per expert (25 * 128)
#define MR_ 3136          // real rows per expert (64 * 49)
#define MT_ 25600         // total padded rows
#define KH_ 4             // gate1 K-split
#define HP_ 768           // tier-B GEMM H-pass chunk
#define HCF_ 384          // fallback (round-1) H chunk
#define NPF_ 8

using bf16x8 = __attribute__((ext_vector_type(8))) short;
using f32x4  = __attribute__((ext_vector_type(4))) float;

__device__ __forceinline__ unsigned short f2bf(float v) {
    __hip_bfloat16 h = __float2bfloat16(v);
    return __builtin_bit_cast(unsigned short, h);
}
__device__ __forceinline__ float bf2f(unsigned short u) {
    unsigned int w = ((unsigned int)u) << 16;
    return __builtin_bit_cast(float, w);
}
__device__ __forceinline__ unsigned int add2bf(unsigned int a, unsigned int b) {
    float al = bf2f((unsigned short)(a & 0xffff)), ah = bf2f((unsigned short)(a >> 16));
    float bl = bf2f((unsigned short)(b & 0xffff)), bh = bf2f((unsigned short)(b >> 16));
    return (unsigned int)f2bf(al + bl) | ((unsigned int)f2bf(ah + bh) << 16);
}

// async global->LDS, 16B per lane; LDS dest = wave-uniform base + lane*16
#define GLL16(g, l) __builtin_amdgcn_global_load_lds( \
    (const __attribute__((address_space(1))) unsigned int*)(uintptr_t)(g), \
    (__attribute__((address_space(3))) unsigned int*)(uintptr_t)(l), 16, 0, 0)

// m204 bijective XCD swizzle
__device__ __forceinline__ int xcd_swz(int bid, int nblk) {
    int q = nblk >> 3, r = nblk & 7;
    int xcd = bid & 7, idx = bid >> 3;
    int base = (xcd < r) ? xcd * (q + 1) : r * (q + 1) + (xcd - r) * q;
    return base + idx;
}

// ---------------- out = -x (fallback path only) ----------------
__global__ void k_init_out(const float* __restrict__ x, float* __restrict__ out) {
    int i = blockIdx.x * blockDim.x + threadIdx.x;
    const float4* xv = (const float4*)x;
    float4* ov = (float4*)out;
    float4 v = xv[i];
    ov[i] = make_float4(-v.x, -v.y, -v.z, -v.w);
}

// ---------------- gate layer1 (R7-v3 loop + coalesced LDS-transpose epilogue) ----------------
__global__ __launch_bounds__(256) void k_gate1(
        const float* __restrict__ x, const float* __restrict__ Wg1,
        float* __restrict__ gs_part) {
    __shared__ float xs[32][68];     // [k][m], pad 68
    __shared__ float wt[32][200];    // [k][n], pad 200 (also epilogue scratch)
    int bm = blockIdx.x % 197, kh = blockIdx.x / 197;
    int m0 = bm * 64, k0 = kh * (F_ / KH_);
    int tid = threadIdx.x, lane = tid & 63, wid = tid >> 6;
    int mg = lane & 15;
    int ng = (lane >> 4) + 4 * wid;
    f32x4 acc[4][3] = {};

    int xr = tid >> 3, xc = tid & 7;
    float4 xreg0, xreg1;
    float4 wreg[6];

    auto loadRegs = [&](int t) {
        int kb = k0 + t * 32;
        xreg0 = *(const float4*)(x + (size_t)(m0 + xr) * F_ + kb + xc * 4);
        xreg1 = *(const float4*)(x + (size_t)(m0 + xr + 32) * F_ + kb + xc * 4);
        #pragma unroll
        for (int i = 0; i < 6; ++i) {
            int idx = tid + i * 256;
            int kr = idx / 48, nc = idx % 48;
            wreg[i] = *(const float4*)(Wg1 + (size_t)(kb + kr) * G_ + nc * 4);
        }
    };
    auto writeLDS = [&]() {
        xs[xc * 4 + 0][xr] = xreg0.x;  xs[xc * 4 + 1][xr] = xreg0.y;
        xs[xc * 4 + 2][xr] = xreg0.z;  xs[xc * 4 + 3][xr] = xreg0.w;
        xs[xc * 4 + 0][xr + 32] = xreg1.x;  xs[xc * 4 + 1][xr + 32] = xreg1.y;
        xs[xc * 4 + 2][xr + 32] = xreg1.z;  xs[xc * 4 + 3][xr + 32] = xreg1.w;
        #pragma unroll
        for (int i = 0; i < 6; ++i) {
            int idx = tid + i * 256;
            int kr = idx / 48, nc = idx % 48;
            *(float4*)&wt[kr][nc * 4] = wreg[i];
        }
    };

    loadRegs(0);
    for (int t = 0; t < 6; ++t) {
        __syncthreads();
        writeLDS();
        __syncthreads();
        if (t < 5) loadRegs(t + 1);
        #pragma unroll
        for (int k = 0; k < 32; ++k) {
            float4 av = *(const float4*)&xs[k][mg * 4];
            f32x4 b0 = *(const f32x4*)&wt[k][ng * 12];
            f32x4 b1 = *(const f32x4*)&wt[k][ng * 12 + 4];
            f32x4 b2 = *(const f32x4*)&wt[k][ng * 12 + 8];
            float am[4] = {av.x, av.y, av.z, av.w};
            #pragma unroll
            for (int mi = 0; mi < 4; ++mi) {
                acc[mi][0] += b0 * am[mi];
                acc[mi][1] += b1 * am[mi];
                acc[mi][2] += b2 * am[mi];
            }
        }
    }
    // coalesced epilogue: 2 chunks of 32 rows via LDS scratch (wt is dead)
    float* scratch = &wt[0][0];
    #pragma unroll
    for (int ch = 0; ch < 2; ++ch) {
        __syncthreads();
        if ((mg >> 3) == ch) {
            int lr = (mg & 7) * 4;
            #pragma unroll
            for (int mi = 0; mi < 4; ++mi) {
                float* rp = scratch + (size_t)(lr + mi) * 196 + ng * 12;
                *(f32x4*)(rp + 0) = acc[mi][0];
                *(f32x4*)(rp + 4) = acc[mi][1];
                *(f32x4*)(rp + 8) = acc[mi][2];
            }
        }
        __syncthreads();
        float* gp = gs_part + (size_t)kh * TB_ * G_ + (size_t)(m0 + ch * 32) * G_;
        #pragma unroll
        for (int i = 0; i < 6; ++i) {
            int idx = tid + i * 256;
            int r = idx / 48, c4 = idx % 48;
            *(float4*)(gp + (size_t)r * G_ + c4 * 4) =
                *(const float4*)(scratch + (size_t)r * 196 + c4 * 4);
        }
    }
}

// ---------------- gate layer2: reduce 4 partials + bias + relu -> logits -> softmax -> top2 ----------------
__global__ __launch_bounds__(256) void k_gate2(
        const float* __restrict__ gs_part, const float* __restrict__ bg1,
        const float* __restrict__ Wg2, const float* __restrict__ bg2,
        float* __restrict__ cw, int* __restrict__ ecnt) {
    __shared__ float gsh[32][200];
    __shared__ float wg2s[G_ * N_];
    __shared__ float lg[32][8];
    int tid = threadIdx.x;
    int id0 = blockIdx.x * 32;

    for (int i = tid; i < 32 * 48; i += 256) {
        int r = i / 48, c4 = i % 48;
        const float* p0 = gs_part + (size_t)(id0 + r) * G_ + c4 * 4;
        float4 g = *(const float4*)(bg1 + c4 * 4);
        float4 v = g;
        #pragma unroll
        for (int p = 0; p < KH_; ++p) {
            float4 a = *(const float4*)(p0 + (size_t)p * TB_ * G_);
            v.x += a.x; v.y += a.y; v.z += a.z; v.w += a.w;
        }
        v.x = fmaxf(v.x, 0.f); v.y = fmaxf(v.y, 0.f);
        v.z = fmaxf(v.z, 0.f); v.w = fmaxf(v.w, 0.f);
        ((float4*)&gsh[r][0])[c4] = v;
    }
    for (int i = tid; i < G_ * N_; i += 256) wg2s[i] = Wg2[i];
    __syncthreads();

    int tk = tid >> 3, n = tid & 7;
    float a = bg2[n];
    for (int k = 0; k < G_; ++k) a += gsh[tk][k] * wg2s[k * N_ + n];
    lg[tk][n] = a;
    __syncthreads();

    if (tid < 32) {
        int tk2 = tid;
        float p[8];
        float m = lg[tk2][0];
        #pragma unroll
        for (int nn = 1; nn < 8; ++nn) m = fmaxf(m, lg[tk2][nn]);
        float s = 0.f;
        #pragma unroll
        for (int nn = 0; nn < 8; ++nn) { p[nn] = expf(lg[tk2][nn] - m); s += p[nn]; }
        float inv = 1.f / s;
        #pragma unroll
        for (int nn = 0; nn < 8; ++nn) p[nn] *= inv;
        int i1 = 0; float v1 = p[0];
        #pragma unroll
        for (int nn = 1; nn < 8; ++nn) if (p[nn] > v1) { v1 = p[nn]; i1 = nn; }
        int i2 = -1; float v2 = -1.f;
        #pragma unroll
        for (int nn = 0; nn < 8; ++nn) if (nn != i1 && p[nn] > v2) { v2 = p[nn]; i2 = nn; }
        int id = id0 + tk2;
        int t = id / B_, b = id % B_;
        ecnt[id] = 0;
        #pragma unroll
        for (int nn = 0; nn < 8; ++nn) {
            float v = (nn == i1 || nn == i2) ? p[nn] : 0.f;
            cw[((size_t)(b * N_ + nn)) * T_ + t] = v;
        }
    }
}

// ---------------- gate (fallback path only) ----------------
__global__ __launch_bounds__(256) void k_gate(
        const float* __restrict__ x, const float* __restrict__ Wg1,
        const float* __restrict__ bg1, const float* __restrict__ Wg2,
        const float* __restrict__ bg2, float* __restrict__ cw,
        int* __restrict__ ecnt) {
    __shared__ float xsh[8][F_];
    __shared__ float gsl[8][G_];
    __shared__ float lg[8][N_];
    int tid = threadIdx.x;
    int id0 = blockIdx.x * 8;

    int gid = blockIdx.x * 256 + tid;
    if (gid < TB_ && ecnt) ecnt[gid] = 0;

    const float4* xv = (const float4*)(x + (size_t)id0 * F_);
    float4* xshv = (float4*)&xsh[0][0];
    for (int idx = tid; idx < 8 * (F_/4); idx += 256) xshv[idx] = xv[idx];
    __syncthreads();

    if (tid < G_) {
        float acc[8];
        float bb = bg1[tid];
        #pragma unroll
        for (int tk = 0; tk < 8; ++tk) acc[tk] = bb;
        for (int k = 0; k < F_; ++k) {
            float w = Wg1[k * G_ + tid];
            #pragma unroll
            for (int tk = 0; tk < 8; ++tk) acc[tk] += xsh[tk][k] * w;
        }
        #pragma unroll
        for (int tk = 0; tk < 8; ++tk) gsl[tk][tid] = fmaxf(acc[tk], 0.f);
    }
    __syncthreads();

    if (tid < 64) {
        int tk = tid >> 3, n = tid & 7;
        float acc = bg2[n];
        for (int k = 0; k < G_; ++k) acc += gsl[tk][k] * Wg2[k * N_ + n];
        lg[tk][n] = acc;
    }
    __syncthreads();

    if (tid < 8) {
        int tk = tid;
        float p[8];
        float m = lg[tk][0];
        #pragma unroll
        for (int n = 1; n < 8; ++n) m = fmaxf(m, lg[tk][n]);
        float s = 0.f;
        #pragma unroll
        for (int n = 0; n < 8; ++n) { p[n] = expf(lg[tk][n] - m); s += p[n]; }
        float inv = 1.f / s;
        #pragma unroll
        for (int n = 0; n < 8; ++n) p[n] *= inv;
        int i1 = 0; float v1 = p[0];
        #pragma unroll
        for (int n = 1; n < 8; ++n) if (p[n] > v1) { v1 = p[n]; i1 = n; }
        int i2 = -1; float v2 = -1.f;
        #pragma unroll
        for (int n = 0; n < 8; ++n) if (n != i1 && p[n] > v2) { v2 = p[n]; i2 = n; }
        int id = id0 + tk;
        int t = id / B_, b = id % B_;
        #pragma unroll
        for (int n = 0; n < 8; ++n) {
            float v = (n == i1 || n == i2) ? p[n] : 0.f;
            cw[((size_t)(b * N_ + n)) * T_ + t] = v;
        }
    }
}

// ---------------- capacity: exact top-CAP rank per (b,n); builds inverse map ----------------
__global__ __launch_bounds__(256) void k_capacity(
        const float* __restrict__ cw, int* __restrict__ toks,
        float* __restrict__ wts, int* __restrict__ counts,
        int* __restrict__ ecnt, int* __restrict__ erow) {
    __shared__ float v[T_];
    __shared__ int keep[T_];
    int tid = threadIdx.x;
    int bn = blockIdx.x;
    int b = bn >> 3, n = bn & 7;
    if (tid < T_) v[tid] = cw[(size_t)bn * T_ + tid];
    __syncthreads();
    int kp = 0; float my = 0.f;
    if (tid < T_) {
        my = v[tid];
        int rank = 0;
        for (int t2 = 0; t2 < T_; ++t2) {
            float vt = v[t2];
            rank += (vt > my) || (vt == my && t2 < tid);
        }
        kp = (rank < CAP_) && (my > 0.f);
    }
    if (tid < T_) keep[tid] = kp;
    __syncthreads();
    if (tid < T_ && kp) {
        int slot = 0;
        for (int t2 = 0; t2 < T_; ++t2) slot += (t2 < tid) ? keep[t2] : 0;
        toks[bn * CAP_ + slot] = tid;
        wts[bn * CAP_ + slot] = my;
        if (ecnt) {
            int orow = tid * B_ + b;
            int pos = atomicAdd(&ecnt[orow], 1);
            erow[orow * 2 + pos] = n * ME_ + b * CAP_ + slot;
        }
    }
    if (tid == 0) {
        int tot = 0;
        for (int t2 = 0; t2 < T_; ++t2) tot += keep[t2];
        counts[bn] = tot;
    }
}

// ---------------- repack W [E][K][J] fp32 -> WT [E][J][K] bf16, pre-swizzled ----------------
__global__ __launch_bounds__(256) void k_repack(
        const float* __restrict__ W, unsigned short* __restrict__ WT, int K, int J) {
    __shared__ float tile[64][65];
    int bid = blockIdx.x;
    int nk = K >> 6, nj = J >> 6;
    int kt = bid % nk; bid /= nk;
    int jt = bid % nj; int e = bid / nj;
    int k0 = kt * 64, j0 = jt * 64;
    int tid = threadIdx.x;
    int jr = (tid & 15) << 2;
    int kr = tid >> 4;
    const float* src = W + ((size_t)e * K + k0) * J + j0;
    #pragma unroll
    for (int i = 0; i < 4; ++i) {
        float4 v = *(const float4*)(src + (size_t)(kr + 16 * i) * J + jr);
        *(float4*)&tile[kr + 16 * i][jr] = v;
    }
    __syncthreads();
    int c = tid & 7;
    int jrow = tid >> 3;
    #pragma unroll
    for (int i = 0; i < 2; ++i) {
        int j = jrow + 32 * i;
        float f[8];
        #pragma unroll
        for (int s = 0; s < 8; ++s) f[s] = tile[c * 8 + s][j];
        uint4 u;
        u.x = f2bf(f[0]) | ((unsigned)f2bf(f[1]) << 16);
        u.y = f2bf(f[2]) | ((unsigned)f2bf(f[3]) << 16);
        u.z = f2bf(f[4]) | ((unsigned)f2bf(f[5]) << 16);
        u.w = f2bf(f[6]) | ((unsigned)f2bf(f[7]) << 16);
        int jg = j0 + j;
        char* drow = (char*)WT + ((size_t)e * J + jg) * (size_t)K * 2 + (size_t)(k0 >> 6) * 128;
        *(uint4*)(drow + ((c << 4) ^ ((jg & 7) << 4))) = u;
    }
}

// ---------------- gather x rows -> Xg [MT_][768] bf16, pre-swizzled, zero-padded ----------------
__global__ __launch_bounds__(256) void k_gather(
        const float* __restrict__ x, const int* __restrict__ toks,
        const int* __restrict__ counts, unsigned short* __restrict__ Xg) {
    int gi = blockIdx.x * 256 + threadIdx.x;
    int R = gi / 96, c = gi - R * 96;
    int e = R / ME_, re = R - e * ME_;
    uint4 val = make_uint4(0u, 0u, 0u, 0u);
    if (re < MR_) {
        int g = re / CAP_, slot = re - g * CAP_;
        int bn = g * N_ + e;
        if (slot < counts[bn]) {
            int t = toks[bn * CAP_ + slot];
            const float* xp = x + ((size_t)t * B_ + g) * F_ + c * 8;
            float4 v0 = *(const float4*)xp;
            float4 v1 = *(const float4*)(xp + 4);
            val.x = f2bf(v0.x) | ((unsigned)f2bf(v0.y) << 16);
            val.y = f2bf(v0.z) | ((unsigned)f2bf(v0.w) << 16);
            val.z = f2bf(v1.x) | ((unsigned)f2bf(v1.y) << 16);
            val.w = f2bf(v1.z) | ((unsigned)f2bf(v1.w) << 16);
        }
    }
    int w = (c * 16) & 127;
    char* dst = (char*)Xg + (size_t)R * 1536 + (c >> 3) * 128 + (w ^ ((R & 7) << 4));
    *(uint4*)dst = val;
}

// ---------------- GEMM1 (templated): Hg cols = relu(W1T . Xg^T + b1) ----------------
template<int NJT, int HSTRIDE>
__global__ __launch_bounds__(256) void k_gemm1(
        const unsigned short* __restrict__ W1T, const unsigned short* __restrict__ Xg,
        const float* __restrict__ b1, unsigned short* __restrict__ Hg,
        int jofs, int nblk) {
    __shared__ char ldsA[2][16384];
    __shared__ char ldsB[2][16384];
    int swzb = xcd_swz(blockIdx.x, nblk);
    const int per_e = 25 * NJT;
    int e = swzb / per_e;
    int rem = swzb - e * per_e;
    int mt = rem / NJT, jtl = rem % NJT;
    int jt = jofs + jtl;
    int tid = threadIdx.x, lane = tid & 63, wid = tid >> 6;
    int lr8 = lane >> 3, sl = (lane & 7) << 4;
    const char* Ab = (const char*)W1T + ((size_t)e * H_ + (size_t)jt * 128) * (F_ * 2);
    const char* Bb = (const char*)Xg + ((size_t)e * ME_ + (size_t)mt * 128) * (F_ * 2);
    f32x4 acc[4][4] = {};
    int swz = (lane & 7) << 4;
    int q16 = (lane >> 4) << 4;

    auto stage = [&](int buf, int it) {
        int kb = it << 7;
        #pragma unroll
        for (int i = 0; i < 4; ++i) {
            int lr = wid * 32 + i * 8 + lr8;
            GLL16(Ab + (size_t)lr * 1536 + kb + sl, ldsA[buf] + (wid * 32 + i * 8) * 128);
            GLL16(Bb + (size_t)lr * 1536 + kb + sl, ldsB[buf] + (wid * 32 + i * 8) * 128);
        }
    };

    stage(0, 0);
    __syncthreads();
    int cur = 0;
    #pragma unroll 1
    for (int it = 0; it < 12; ++it) {
        if (it < 11) stage(cur ^ 1, it + 1);
        const char* la = ldsA[cur] + ((wid & 1) * 64) * 128;
        const char* lb = ldsB[cur] + ((wid >> 1) * 64) * 128;
        #pragma unroll
        for (int ks = 0; ks < 2; ++ks) {
            bf16x8 af[4], bfr[4];
            int kk = (ks * 64 + q16) ^ swz;
            #pragma unroll
            for (int t = 0; t < 4; ++t) {
                int ro = (16 * t + (lane & 15)) * 128;
                af[t]  = *(const bf16x8*)(la + ro + kk);
                bfr[t] = *(const bf16x8*)(lb + ro + kk);
            }
            #pragma unroll
            for (int ti = 0; ti < 4; ++ti)
                #pragma unroll
                for (int tm = 0; tm < 4; ++tm)
                    acc[ti][tm] = __builtin_amdgcn_mfma_f32_16x16x32_bf16(af[ti], bfr[tm], acc[ti][tm], 0, 0, 0);
        }
        __syncthreads();
        cur ^= 1;
    }
    char* tile = &ldsA[0][0];
    int jl0 = (wid & 1) * 64;
    int ml0 = (wid >> 1) * 64;
    const float* b1p = b1 + (size_t)e * H_ + (size_t)jt * 128;
    #pragma unroll
    for (int tj = 0; tj < 4; ++tj) {
        int jc = jl0 + 16 * tj + ((lane >> 4) << 2);
        float bb0 = b1p[jc], bb1 = b1p[jc + 1], bb2 = b1p[jc + 2], bb3 = b1p[jc + 3];
        #pragma unroll
        for (int tm = 0; tm < 4; ++tm) {
            int m = ml0 + 16 * tm + (lane & 15);
            f32x4 a = acc[tj][tm];
            unsigned int u0 = f2bf(fmaxf(a[0] + bb0, 0.f)) | ((unsigned)f2bf(fmaxf(a[1] + bb1, 0.f)) << 16);
            unsigned int u1 = f2bf(fmaxf(a[2] + bb2, 0.f)) | ((unsigned)f2bf(fmaxf(a[3] + bb3, 0.f)) << 16);
            int bcol = jc * 2;
            int w = bcol & 127;
            *(uint2*)(tile + m * 256 + (bcol & ~127) + (w ^ ((m & 7) << 4))) = make_uint2(u0, u1);
        }
    }
    __syncthreads();
    char* Hrow = (char*)Hg + ((size_t)e * ME_ + (size_t)mt * 128) * HSTRIDE + (size_t)jtl * 256;
    #pragma unroll
    for (int i = 0; i < 8; ++i) {
        int idx = tid + i * 256;
        int r = idx >> 4, c = (idx & 15) << 4;
        *(uint4*)(Hrow + (size_t)r * HSTRIDE + c) = *(const uint4*)(tile + r * 256 + c);
    }
}

// ---------------- GEMM2 (templated): Og (+)= fw * (W2T[K-slice] . Hg^T) (+fw*b2 when kofsB==0) ----------------
template<int KITERS, int BSTRIDE>
__global__ __launch_bounds__(256) void k_gemm2(
        const unsigned short* __restrict__ W2T, const unsigned short* __restrict__ Hg,
        const float* __restrict__ b2, const float* __restrict__ wts,
        const int* __restrict__ counts, unsigned short* __restrict__ Og,
        int kofsB, int nblk) {
    __shared__ char ldsA[2][16384];
    __shared__ char ldsB[2][16384];
    int swzb = xcd_swz(blockIdx.x, nblk);
    int e = swzb / 150;
    int rem = swzb - e * 150;
    int mt = rem / 6, ft = rem % 6;
    int tid = threadIdx.x, lane = tid & 63, wid = tid >> 6;
    int lr8 = lane >> 3, sl = (lane & 7) << 4;
    const char* Ab = (const char*)W2T + ((size_t)e * F_ + (size_t)ft * 128) * (H_ * 2) + kofsB;
    const char* Bb = (const char*)Hg + ((size_t)e * ME_ + (size_t)mt * 128) * BSTRIDE;
    f32x4 acc[4][4] = {};
    int swz = (lane & 7) << 4;
    int q16 = (lane >> 4) << 4;

    auto stage = [&](int buf, int it) {
        int kb = it << 7;
        #pragma unroll
        for (int i = 0; i < 4; ++i) {
            int lr = wid * 32 + i * 8 + lr8;
            GLL16(Ab + (size_t)lr * 6144 + kb + sl, ldsA[buf] + (wid * 32 + i * 8) * 128);
            GLL16(Bb + (size_t)lr * BSTRIDE + kb + sl, ldsB[buf] + (wid * 32 + i * 8) * 128);
        }
    };

    stage(0, 0);
    __syncthreads();
    int cur = 0;
    #pragma unroll 1
    for (int it = 0; it < KITERS; ++it) {
        if (it < KITERS - 1) stage(cur ^ 1, it + 1);
        const char* la = ldsA[cur] + ((wid & 1) * 64) * 128;
        const char* lb = ldsB[cur] + ((wid >> 1) * 64) * 128;
        #pragma unroll
        for (int ks = 0; ks < 2; ++ks) {
            bf16x8 af[4], bfr[4];
            int kk = (ks * 64 + q16) ^ swz;
            #pragma unroll
            for (int t = 0; t < 4; ++t) {
                int ro = (16 * t + (lane & 15)) * 128;
                af[t]  = *(const bf16x8*)(la + ro + kk);
                bfr[t] = *(const bf16x8*)(lb + ro + kk);
            }
            #pragma unroll
            for (int ti = 0; ti < 4; ++ti)
                #pragma unroll
                for (int tm = 0; tm < 4; ++tm)
                    acc[ti][tm] = __builtin_amdgcn_mfma_f32_16x16x32_bf16(af[ti], bfr[tm], acc[ti][tm], 0, 0, 0);
        }
        __syncthreads();
        cur ^= 1;
    }
    char* tile = &ldsA[0][0];
    int fl0 = (wid & 1) * 64;
    int ml0 = (wid >> 1) * 64;
    const float* b2p = b2 + (size_t)e * F_ + (size_t)ft * 128;
    float fwv[4];
    #pragma unroll
    for (int tm = 0; tm < 4; ++tm) {
        int mloc = ml0 + 16 * tm + (lane & 15);
        int re = mt * 128 + mloc;
        float fw = 0.f;
        if (re < MR_) {
            int g = re / CAP_;
            int slot = re - g * CAP_;
            int bn = g * N_ + e;
            if (slot < counts[bn]) fw = wts[bn * CAP_ + slot];
        }
        fwv[tm] = fw;
    }
    int p0 = (kofsB == 0);
    #pragma unroll
    for (int tf = 0; tf < 4; ++tf) {
        int fc = fl0 + 16 * tf + ((lane >> 4) << 2);
        float c0 = 0.f, c1 = 0.f, c2 = 0.f, c3 = 0.f;
        if (p0) { c0 = b2p[fc]; c1 = b2p[fc + 1]; c2 = b2p[fc + 2]; c3 = b2p[fc + 3]; }
        #pragma unroll
        for (int tm = 0; tm < 4; ++tm) {
            int mloc = ml0 + 16 * tm + (lane & 15);
            f32x4 a = acc[tf][tm];
            float fw = fwv[tm];
            unsigned int u0 = f2bf(fw * (a[0] + c0)) | ((unsigned)f2bf(fw * (a[1] + c1)) << 16);
            unsigned int u1 = f2bf(fw * (a[2] + c2)) | ((unsigned)f2bf(fw * (a[3] + c3)) << 16);
            int bcol = fc * 2;
            int w = bcol & 127;
            *(uint2*)(tile + mloc * 256 + (bcol & ~127) + (w ^ ((mloc & 7) << 4))) = make_uint2(u0, u1);
        }
    }
    __syncthreads();
    char* Orow = (char*)Og + ((size_t)e * ME_ + (size_t)mt * 128) * (F_ * 2) + (size_t)ft * 256;
    if (KITERS == 48 || p0) {
        #pragma unroll
        for (int i = 0; i < 8; ++i) {
            int idx = tid + i * 256;
            int r = idx >> 4, c = (idx & 15) << 4;
            const char* src = tile + r * 256 + (c & ~127) + ((c & 127) ^ ((r & 7) << 4));
            *(uint4*)(Orow + (size_t)r * (F_ * 2) + c) = *(const uint4*)src;
        }
    } else {
        #pragma unroll
        for (int i = 0; i < 8; ++i) {
            int idx = tid + i * 256;
            int r = idx >> 4, c = (idx & 15) << 4;
            const char* src = tile + r * 256 + (c & ~127) + ((c & 127) ^ ((r & 7) << 4));
            uint4 nw = *(const uint4*)src;
            uint4* dst = (uint4*)(Orow + (size_t)r * (F_ * 2) + c);
            uint4 old = *dst;
            uint4 res;
            res.x = add2bf(old.x, nw.x);
            res.y = add2bf(old.y, nw.y);
            res.z = add2bf(old.z, nw.z);
            res.w = add2bf(old.w, nw.w);
            *dst = res;
        }
    }
}

// ---------------- combine: out[t,b,:] = sum(og entries) - x ----------------
__global__ __launch_bounds__(256) void k_combine(
        const float* __restrict__ x, const unsigned short* __restrict__ Og,
        const int* __restrict__ ecnt, const int* __restrict__ erow,
        float* __restrict__ out) {
    int idx = blockIdx.x * 256 + threadIdx.x;
    int row = idx / 192, c4 = idx - row * 192;
    float4 s = make_float4(0.f, 0.f, 0.f, 0.f);
    int c = ecnt[row];
    if (c > 0) {
        ushort4 u = *(const ushort4*)(Og + (size_t)erow[row * 2] * F_ + c4 * 4);
        s.x += bf2f(u.x); s.y += bf2f(u.y); s.z += bf2f(u.z); s.w += bf2f(u.w);
    }
    if (c > 1) {
        ushort4 u = *(const ushort4*)(Og + (size_t)erow[row * 2 + 1] * F_ + c4 * 4);
        s.x += bf2f(u.x); s.y += bf2f(u.y); s.z += bf2f(u.z); s.w += bf2f(u.w);
    }
    float4 xv = ((const float4*)x)[idx];
    ((float4*)out)[idx] = make_float4(s.x - xv.x, s.y - xv.y, s.z - xv.z, s.w - xv.w);
}

// ================= round-1 fallback kernels (tiny ws only) =================
__global__ __launch_bounds__(HCF_) void k_fc1(
        const float* __restrict__ x, const float* __restrict__ W1,
        const float* __restrict__ b1, const int* __restrict__ toks,
        const int* __restrict__ counts, __hip_bfloat16* __restrict__ h, int pass) {
    __shared__ float xs[25][F_];
    int tid = threadIdx.x;
    int bn = blockIdx.x >> 1;
    int half = blockIdx.x & 1;
    int r0 = half * 25;
    int b = bn >> 3, n = bn & 7;
    int c = counts[bn];
    for (int idx = tid; idx < 25 * (F_/4); idx += HCF_) {
        int r = idx / (F_/4), k4 = idx % (F_/4);
        int gr = r0 + r;
        float4 val = make_float4(0.f, 0.f, 0.f, 0.f);
        if (gr < c) {
            int t = toks[bn * CAP_ + gr];
            val = ((const float4*)(x + ((size_t)(t * B_ + b)) * F_))[k4];
        }
        ((float4*)&xs[r][0])[k4] = val;
    }
    __syncthreads();
    int j = pass * HCF_ + tid;
    const float* w1p = W1 + (size_t)n * F_ * H_ + j;
    float bias = b1[n * H_ + j];
    float acc[25];
    #pragma unroll
    for (int r = 0; r < 25; ++r) acc[r] = bias;
    const float4* xsv = (const float4*)&xs[0][0];
    for (int k4 = 0; k4 < F_/4; ++k4) {
        float w0 = w1p[(size_t)(4*k4+0) * H_];
        float w1v = w1p[(size_t)(4*k4+1) * H_];
        float w2v = w1p[(size_t)(4*k4+2) * H_];
        float w3v = w1p[(size_t)(4*k4+3) * H_];
        #pragma unroll
        for (int r = 0; r < 25; ++r) {
            float4 xv = xsv[r * (F_/4) + k4];
            acc[r] += xv.x*w0 + xv.y*w1v + xv.z*w2v + xv.w*w3v;
        }
    }
    __hip_bfloat16* hp = h + ((size_t)bn * CAP_ + r0) * HCF_ + tid;
    #pragma unroll
    for (int r = 0; r < 25; ++r) {
        int gr = r0 + r;
        if (gr < CAP_) hp[(size_t)r * HCF_] = __float2bfloat16(fmaxf(acc[r], 0.f));
    }
}

__global__ __launch_bounds__(768) void k_fc2(
        const float* __restrict__ W2, const float* __restrict__ b2,
        const int* __restrict__ toks, const float* __restrict__ wts,
        const int* __restrict__ counts, const __hip_bfloat16* __restrict__ h,
        float* __restrict__ out, int pass) {
    __shared__ float hs[CAP_][HCF_];
    int tid = threadIdx.x;
    int bn = blockIdx.x;
    int c = counts[bn];
    if (c == 0) return;
    int b = bn >> 3, n = bn & 7;
    const ushort4* hv = (const ushort4*)(h + (size_t)bn * CAP_ * HCF_);
    for (int idx = tid; idx < CAP_ * (HCF_/4); idx += 768) {
        ushort4 u = hv[idx];
        float4 fv;
        fv.x = __bfloat162float(*(const __hip_bfloat16*)&u.x);
        fv.y = __bfloat162float(*(const __hip_bfloat16*)&u.y);
        fv.z = __bfloat162float(*(const __hip_bfloat16*)&u.z);
        fv.w = __bfloat162float(*(const __hip_bfloat16*)&u.w);
        ((float4*)&hs[0][0])[idx] = fv;
    }
    __syncthreads();
    int f = tid;
    const float* w2p = W2 + (size_t)n * H_ * F_ + (size_t)(pass * HCF_) * F_ + f;
    float acc[CAP_];
    #pragma unroll
    for (int r = 0; r < CAP_; ++r) acc[r] = 0.f;
    for (int j4 = 0; j4 < HCF_/4; ++j4) {
        float w0 = w2p[(size_t)(4*j4+0) * F_];
        float w1v = w2p[(size_t)(4*j4+1) * F_];
        float w2v = w2p[(size_t)(4*j4+2) * F_];
        float w3v = w2p[(size_t)(4*j4+3) * F_];
        #pragma unroll
        for (int r = 0; r < CAP_; ++r) {
            float4 hh = ((const float4*)&hs[r][0])[j4];
            acc[r] += hh.x*w0 + hh.y*w1v + hh.z*w2v + hh.w*w3v;
        }
    }
    float bias = (pass == 0) ? b2[n * F_ + f] : 0.f;
    #pragma unroll
    for (int r = 0; r < CAP_; ++r) {
        if (r < c) {
            int t = toks[bn * CAP_ + r];
            float fw = wts[bn * CAP_ + r];
            atomicAdd(&out[((size_t)(t * B_ + b)) * F_ + f], fw * (acc[r] + bias));
        }
    }
}

extern "C" void kernel_launch(void* const* d_in, const int* in_sizes, int n_in,
                              void* d_out, int out_size, void* d_ws, size_t ws_size,
                              hipStream_t stream) {
    const float* x   = (const float*)d_in[0];
    const float* Wg1 = (const float*)d_in[1];
    const float* bg1 = (const float*)d_in[2];
    const float* Wg2 = (const float*)d_in[3];
    const float* bg2 = (const float*)d_in[4];
    const float* W1  = (const float*)d_in[5];
    const float* b1  = (const float*)d_in[6];
    const float* W2  = (const float*)d_in[7];
    const float* b2  = (const float*)d_in[8];
    float* out = (float*)d_out;

    // ws layout (Og aliases Xg in tier A; separate in tier B)
    size_t oW1T  = 0;
    size_t oW2T  = oW1T + (size_t)N_ * H_ * F_ * 2;     // 37.75 MB
    size_t oXg   = oW2T + (size_t)N_ * H_ * F_ * 2;     // 75.5 MB
    size_t oCw   = oXg  + (size_t)MT_ * F_ * 2;         // +39.3 MB
    size_t oWts  = oCw  + (size_t)NBN_ * T_ * 4;
    size_t oTok  = oWts + (size_t)NBN_ * CAP_ * 4;
    size_t oCnt  = oTok + (size_t)NBN_ * CAP_ * 4;
    size_t oEcnt = oCnt + (size_t)NBN_ * 4;
    size_t oErow = oEcnt + (size_t)TB_ * 4;
    size_t oHg   = oErow + (size_t)TB_ * 8;             // ~115.6 MB
    size_t needA = oHg + (size_t)MT_ * H_ * 2;          // ~272.9 MB (full Hg; Og aliases Xg)
    size_t oOgB  = oHg + (size_t)MT_ * HP_ * 2;         // tier-B Og after Hg quarter
    size_t needB = oOgB + (size_t)MT_ * F_ * 2;         // ~194.2 MB

    if (ws_size >= needB) {
        unsigned short* W1T = (unsigned short*)((char*)d_ws + oW1T);
        unsigned short* W2T = (unsigned short*)((char*)d_ws + oW2T);
        unsigned short* Xg  = (unsigned short*)((char*)d_ws + oXg);
        unsigned short* Hg  = (unsigned short*)((char*)d_ws + oHg);
        float* gs_part = (float*)((char*)d_ws + oHg);   // aliases Hg; dead after k_gate2
        float* cw   = (float*)((char*)d_ws + oCw);
        float* wts  = (float*)((char*)d_ws + oWts);
        int* toks   = (int*)((char*)d_ws + oTok);
        int* counts = (int*)((char*)d_ws + oCnt);
        int* ecnt   = (int*)((char*)d_ws + oEcnt);
        int* erow   = (int*)((char*)d_ws + oErow);

        int tierA = (ws_size >= needA);
        unsigned short* Og = tierA ? Xg                     // tier A: Xg dead after single gemm1
                                   : (unsigned short*)((char*)d_ws + oOgB);

        k_gate1<<<197 * KH_, 256, 0, stream>>>(x, Wg1, gs_part);
        k_gate2<<<TB_ / 32, 256, 0, stream>>>(gs_part, bg1, Wg2, bg2, cw, ecnt);
        k_capacity<<<NBN_, 256, 0, stream>>>(cw, toks, wts, counts, ecnt, erow);
        k_repack<<<N_ * (F_/64) * (H_/64), 256, 0, stream>>>(W1, W1T, F_, H_);
        k_repack<<<N_ * (H_/64) * (F_/64), 256, 0, stream>>>(W2, W2T, H_, F_);
        k_gather<<<(MT_ * 96) / 256, 256, 0, stream>>>(x, toks, counts, Xg);
        if (tierA) {
            k_gemm1<24, H_ * 2><<<4800, 256, 0, stream>>>(W1T, Xg, b1, Hg, 0, 4800);
            k_gemm2<48, H_ * 2><<<1200, 256, 0, stream>>>(W2T, Hg, b2, wts, counts, Og, 0, 1200);
        } else {
            for (int p = 0; p < 4; ++p) {
                k_gemm1<6, HP_ * 2><<<1200, 256, 0, stream>>>(W1T, Xg, b1, Hg, p * 6, 1200);
                k_gemm2<12, HP_ * 2><<<1200, 256, 0, stream>>>(W2T, Hg, b2, wts, counts, Og, p * HP_ * 2, 1200);
            }
        }
        k_combine<<<(TB_ * 192) / 256, 256, 0, stream>>>(x, Og, ecnt, erow, out);
    } else {
        // round-1 fallback (~20 MB ws)
        __hip_bfloat16* h = (__hip_bfloat16*)d_ws;
        float* cw  = (float*)((char*)d_ws + (size_t)NBN_ * CAP_ * HCF_ * 2);
        float* wts = cw + (size_t)NBN_ * T_;
        int* toks  = (int*)(wts + NBN_ * CAP_);
        int* counts = toks + NBN_ * CAP_;
        k_init_out<<<(TB_ * F_) / 1024, 256, 0, stream>>>(x, out);
        k_gate<<<TB_ / 8, 256, 0, stream>>>(x, Wg1, bg1, Wg2, bg2, cw, nullptr);
        k_capacity<<<NBN_, 256, 0, stream>>>(cw, toks, wts, counts, nullptr, nullptr);
        for (int p = 0; p < NPF_; ++p) {
            k_fc1<<<NBN_ * 2, HCF_, 0, stream>>>(x, W1, b1, toks, counts, h, p);
            k_fc2<<<NBN_, 768, 0, stream>>>(W2, b2, toks, wts, counts, h, out, p);
        }
    }
}

// Round 17
// 464.445 us; speedup vs baseline: 1.1148x; 1.0675x over previous
//
#include <hip/hip_runtime.h>
#include <hip/hip_bf16.h>
#include <math.h>
#include <stdint.h>

#define T_ 197
#define B_ 64
#define F_ 768
#define N_ 8
#define CAP_ 49
#define H_ 3072
#define G_ 192
#define TB_ (T_*B_)       // 12608
#define NBN_ (B_*N_)      // 512
#define ME_ 3200          // padded rows per expert (25 * 128)
#define MR_ 3136          // real rows per expert (64 * 49)
#define MT_ 25600         // total padded rows
#define KH_ 4             // gate1 K-split
#define HP_ 768           // tier-B GEMM H-pass chunk
#define HCF_ 384          // fallback (round-1) H chunk
#define NPF_ 8
#define G1B_ (197 * KH_)  // 788 gate1 blocks
#define RPB_ 4608         // repack blocks per weight

using bf16x8 = __attribute__((ext_vector_type(8))) short;
using f32x4  = __attribute__((ext_vector_type(4))) float;

__device__ __forceinline__ unsigned short f2bf(float v) {
    __hip_bfloat16 h = __float2bfloat16(v);
    return __builtin_bit_cast(unsigned short, h);
}
__device__ __forceinline__ float bf2f(unsigned short u) {
    unsigned int w = ((unsigned int)u) << 16;
    return __builtin_bit_cast(float, w);
}
__device__ __forceinline__ unsigned int add2bf(unsigned int a, unsigned int b) {
    float al = bf2f((unsigned short)(a & 0xffff)), ah = bf2f((unsigned short)(a >> 16));
    float bl = bf2f((unsigned short)(b & 0xffff)), bh = bf2f((unsigned short)(b >> 16));
    return (unsigned int)f2bf(al + bl) | ((unsigned int)f2bf(ah + bh) << 16);
}

// async global->LDS, 16B per lane; LDS dest = wave-uniform base + lane*16
#define GLL16(g, l) __builtin_amdgcn_global_load_lds( \
    (const __attribute__((address_space(1))) unsigned int*)(uintptr_t)(g), \
    (__attribute__((address_space(3))) unsigned int*)(uintptr_t)(l), 16, 0, 0)

// m204 bijective XCD swizzle
__device__ __forceinline__ int xcd_swz(int bid, int nblk) {
    int q = nblk >> 3, r = nblk & 7;
    int xcd = bid & 7, idx = bid >> 3;
    int base = (xcd < r) ? xcd * (q + 1) : r * (q + 1) + (xcd - r) * q;
    return base + idx;
}

// ---------------- out = -x (fallback path only) ----------------
__global__ void k_init_out(const float* __restrict__ x, float* __restrict__ out) {
    int i = blockIdx.x * blockDim.x + threadIdx.x;
    const float4* xv = (const float4*)x;
    float4* ov = (float4*)out;
    float4 v = xv[i];
    ov[i] = make_float4(-v.x, -v.y, -v.z, -v.w);
}

// ---------------- gate1 body (R7-v3 loop + coalesced LDS-transpose epilogue) ----------------
__device__ __forceinline__ void gate1_body(int bid, char* ldsraw,
        const float* __restrict__ x, const float* __restrict__ Wg1,
        float* __restrict__ gs_part) {
    float (*xs)[68]  = (float(*)[68])ldsraw;                    // 32x68
    float (*wt)[200] = (float(*)[200])(ldsraw + 32 * 68 * 4);   // 32x200
    int bm = bid % 197, kh = bid / 197;
    int m0 = bm * 64, k0 = kh * (F_ / KH_);
    int tid = threadIdx.x, lane = tid & 63, wid = tid >> 6;
    int mg = lane & 15;
    int ng = (lane >> 4) + 4 * wid;
    f32x4 acc[4][3] = {};

    int xr = tid >> 3, xc = tid & 7;
    float4 xreg0, xreg1;
    float4 wreg[6];

    auto loadRegs = [&](int t) {
        int kb = k0 + t * 32;
        xreg0 = *(const float4*)(x + (size_t)(m0 + xr) * F_ + kb + xc * 4);
        xreg1 = *(const float4*)(x + (size_t)(m0 + xr + 32) * F_ + kb + xc * 4);
        #pragma unroll
        for (int i = 0; i < 6; ++i) {
            int idx = tid + i * 256;
            int kr = idx / 48, nc = idx % 48;
            wreg[i] = *(const float4*)(Wg1 + (size_t)(kb + kr) * G_ + nc * 4);
        }
    };
    auto writeLDS = [&]() {
        xs[xc * 4 + 0][xr] = xreg0.x;  xs[xc * 4 + 1][xr] = xreg0.y;
        xs[xc * 4 + 2][xr] = xreg0.z;  xs[xc * 4 + 3][xr] = xreg0.w;
        xs[xc * 4 + 0][xr + 32] = xreg1.x;  xs[xc * 4 + 1][xr + 32] = xreg1.y;
        xs[xc * 4 + 2][xr + 32] = xreg1.z;  xs[xc * 4 + 3][xr + 32] = xreg1.w;
        #pragma unroll
        for (int i = 0; i < 6; ++i) {
            int idx = tid + i * 256;
            int kr = idx / 48, nc = idx % 48;
            *(float4*)&wt[kr][nc * 4] = wreg[i];
        }
    };

    loadRegs(0);
    for (int t = 0; t < 6; ++t) {
        __syncthreads();
        writeLDS();
        __syncthreads();
        if (t < 5) loadRegs(t + 1);
        #pragma unroll
        for (int k = 0; k < 32; ++k) {
            float4 av = *(const float4*)&xs[k][mg * 4];
            f32x4 b0 = *(const f32x4*)&wt[k][ng * 12];
            f32x4 b1 = *(const f32x4*)&wt[k][ng * 12 + 4];
            f32x4 b2 = *(const f32x4*)&wt[k][ng * 12 + 8];
            float am[4] = {av.x, av.y, av.z, av.w};
            #pragma unroll
            for (int mi = 0; mi < 4; ++mi) {
                acc[mi][0] += b0 * am[mi];
                acc[mi][1] += b1 * am[mi];
                acc[mi][2] += b2 * am[mi];
            }
        }
    }
    // coalesced epilogue: 2 chunks of 32 rows via LDS scratch (wt is dead)
    float* scratch = &wt[0][0];
    #pragma unroll
    for (int ch = 0; ch < 2; ++ch) {
        __syncthreads();
        if ((mg >> 3) == ch) {
            int lr = (mg & 7) * 4;
            #pragma unroll
            for (int mi = 0; mi < 4; ++mi) {
                float* rp = scratch + (size_t)(lr + mi) * 196 + ng * 12;
                *(f32x4*)(rp + 0) = acc[mi][0];
                *(f32x4*)(rp + 4) = acc[mi][1];
                *(f32x4*)(rp + 8) = acc[mi][2];
            }
        }
        __syncthreads();
        float* gp = gs_part + (size_t)kh * TB_ * G_ + (size_t)(m0 + ch * 32) * G_;
        #pragma unroll
        for (int i = 0; i < 6; ++i) {
            int idx = tid + i * 256;
            int r = idx / 48, c4 = idx % 48;
            *(float4*)(gp + (size_t)r * G_ + c4 * 4) =
                *(const float4*)(scratch + (size_t)r * 196 + c4 * 4);
        }
    }
}

// ---------------- repack body: W [E][K][J] fp32 -> WT [E][J][K] bf16, pre-swizzled ----------------
__device__ __forceinline__ void repack_body(int bid, char* ldsraw,
        const float* __restrict__ W, unsigned short* __restrict__ WT, int K, int J) {
    float (*tile)[65] = (float(*)[65])ldsraw;   // 64x65
    int nk = K >> 6, nj = J >> 6;
    int kt = bid % nk; bid /= nk;
    int jt = bid % nj; int e = bid / nj;
    int k0 = kt * 64, j0 = jt * 64;
    int tid = threadIdx.x;
    int jr = (tid & 15) << 2;
    int kr = tid >> 4;
    const float* src = W + ((size_t)e * K + k0) * J + j0;
    #pragma unroll
    for (int i = 0; i < 4; ++i) {
        float4 v = *(const float4*)(src + (size_t)(kr + 16 * i) * J + jr);
        *(float4*)&tile[kr + 16 * i][jr] = v;
    }
    __syncthreads();
    int c = tid & 7;
    int jrow = tid >> 3;
    #pragma unroll
    for (int i = 0; i < 2; ++i) {
        int j = jrow + 32 * i;
        float f[8];
        #pragma unroll
        for (int s = 0; s < 8; ++s) f[s] = tile[c * 8 + s][j];
        uint4 u;
        u.x = f2bf(f[0]) | ((unsigned)f2bf(f[1]) << 16);
        u.y = f2bf(f[2]) | ((unsigned)f2bf(f[3]) << 16);
        u.z = f2bf(f[4]) | ((unsigned)f2bf(f[5]) << 16);
        u.w = f2bf(f[6]) | ((unsigned)f2bf(f[7]) << 16);
        int jg = j0 + j;
        char* drow = (char*)WT + ((size_t)e * J + jg) * (size_t)K * 2 + (size_t)(k0 >> 6) * 128;
        *(uint4*)(drow + ((c << 4) ^ ((jg & 7) << 4))) = u;
    }
}

// ---------------- FUSED: gate1 blocks [0,788) + repack W1 [788,5396) + repack W2 [5396,10004) ----------------
__global__ __launch_bounds__(256) void k_fused(
        const float* __restrict__ x, const float* __restrict__ Wg1,
        float* __restrict__ gs_part,
        const float* __restrict__ W1, unsigned short* __restrict__ W1T,
        const float* __restrict__ W2, unsigned short* __restrict__ W2T) {
    __shared__ char lds[32 * 68 * 4 + 32 * 200 * 4];   // 34304 B (gate1 max)
    int bid = blockIdx.x;
    if (bid < G1B_) {
        gate1_body(bid, lds, x, Wg1, gs_part);
    } else if (bid < G1B_ + RPB_) {
        repack_body(bid - G1B_, lds, W1, W1T, F_, H_);
    } else {
        repack_body(bid - G1B_ - RPB_, lds, W2, W2T, H_, F_);
    }
}

// ---------------- gate layer2: reduce 4 partials + bias + relu -> logits -> softmax -> top2 ----------------
__global__ __launch_bounds__(256) void k_gate2(
        const float* __restrict__ gs_part, const float* __restrict__ bg1,
        const float* __restrict__ Wg2, const float* __restrict__ bg2,
        float* __restrict__ cw, int* __restrict__ ecnt) {
    __shared__ float gsh[32][200];
    __shared__ float wg2s[G_ * N_];
    __shared__ float lg[32][8];
    int tid = threadIdx.x;
    int id0 = blockIdx.x * 32;

    for (int i = tid; i < 32 * 48; i += 256) {
        int r = i / 48, c4 = i % 48;
        const float* p0 = gs_part + (size_t)(id0 + r) * G_ + c4 * 4;
        float4 g = *(const float4*)(bg1 + c4 * 4);
        float4 v = g;
        #pragma unroll
        for (int p = 0; p < KH_; ++p) {
            float4 a = *(const float4*)(p0 + (size_t)p * TB_ * G_);
            v.x += a.x; v.y += a.y; v.z += a.z; v.w += a.w;
        }
        v.x = fmaxf(v.x, 0.f); v.y = fmaxf(v.y, 0.f);
        v.z = fmaxf(v.z, 0.f); v.w = fmaxf(v.w, 0.f);
        ((float4*)&gsh[r][0])[c4] = v;
    }
    for (int i = tid; i < G_ * N_; i += 256) wg2s[i] = Wg2[i];
    __syncthreads();

    int tk = tid >> 3, n = tid & 7;
    float a = bg2[n];
    for (int k = 0; k < G_; ++k) a += gsh[tk][k] * wg2s[k * N_ + n];
    lg[tk][n] = a;
    __syncthreads();

    if (tid < 32) {
        int tk2 = tid;
        float p[8];
        float m = lg[tk2][0];
        #pragma unroll
        for (int nn = 1; nn < 8; ++nn) m = fmaxf(m, lg[tk2][nn]);
        float s = 0.f;
        #pragma unroll
        for (int nn = 0; nn < 8; ++nn) { p[nn] = expf(lg[tk2][nn] - m); s += p[nn]; }
        float inv = 1.f / s;
        #pragma unroll
        for (int nn = 0; nn < 8; ++nn) p[nn] *= inv;
        int i1 = 0; float v1 = p[0];
        #pragma unroll
        for (int nn = 1; nn < 8; ++nn) if (p[nn] > v1) { v1 = p[nn]; i1 = nn; }
        int i2 = -1; float v2 = -1.f;
        #pragma unroll
        for (int nn = 0; nn < 8; ++nn) if (nn != i1 && p[nn] > v2) { v2 = p[nn]; i2 = nn; }
        int id = id0 + tk2;
        int t = id / B_, b = id % B_;
        ecnt[id] = 0;
        #pragma unroll
        for (int nn = 0; nn < 8; ++nn) {
            float v = (nn == i1 || nn == i2) ? p[nn] : 0.f;
            cw[((size_t)(b * N_ + nn)) * T_ + t] = v;
        }
    }
}

// ---------------- gate (fallback path only) ----------------
__global__ __launch_bounds__(256) void k_gate(
        const float* __restrict__ x, const float* __restrict__ Wg1,
        const float* __restrict__ bg1, const float* __restrict__ Wg2,
        const float* __restrict__ bg2, float* __restrict__ cw,
        int* __restrict__ ecnt) {
    __shared__ float xsh[8][F_];
    __shared__ float gsl[8][G_];
    __shared__ float lg[8][N_];
    int tid = threadIdx.x;
    int id0 = blockIdx.x * 8;

    int gid = blockIdx.x * 256 + tid;
    if (gid < TB_ && ecnt) ecnt[gid] = 0;

    const float4* xv = (const float4*)(x + (size_t)id0 * F_);
    float4* xshv = (float4*)&xsh[0][0];
    for (int idx = tid; idx < 8 * (F_/4); idx += 256) xshv[idx] = xv[idx];
    __syncthreads();

    if (tid < G_) {
        float acc[8];
        float bb = bg1[tid];
        #pragma unroll
        for (int tk = 0; tk < 8; ++tk) acc[tk] = bb;
        for (int k = 0; k < F_; ++k) {
            float w = Wg1[k * G_ + tid];
            #pragma unroll
            for (int tk = 0; tk < 8; ++tk) acc[tk] += xsh[tk][k] * w;
        }
        #pragma unroll
        for (int tk = 0; tk < 8; ++tk) gsl[tk][tid] = fmaxf(acc[tk], 0.f);
    }
    __syncthreads();

    if (tid < 64) {
        int tk = tid >> 3, n = tid & 7;
        float acc = bg2[n];
        for (int k = 0; k < G_; ++k) acc += gsl[tk][k] * Wg2[k * N_ + n];
        lg[tk][n] = acc;
    }
    __syncthreads();

    if (tid < 8) {
        int tk = tid;
        float p[8];
        float m = lg[tk][0];
        #pragma unroll
        for (int n = 1; n < 8; ++n) m = fmaxf(m, lg[tk][n]);
        float s = 0.f;
        #pragma unroll
        for (int n = 0; n < 8; ++n) { p[n] = expf(lg[tk][n] - m); s += p[n]; }
        float inv = 1.f / s;
        #pragma unroll
        for (int n = 0; n < 8; ++n) p[n] *= inv;
        int i1 = 0; float v1 = p[0];
        #pragma unroll
        for (int n = 1; n < 8; ++n) if (p[n] > v1) { v1 = p[n]; i1 = n; }
        int i2 = -1; float v2 = -1.f;
        #pragma unroll
        for (int n = 0; n < 8; ++n) if (n != i1 && p[n] > v2) { v2 = p[n]; i2 = n; }
        int id = id0 + tk;
        int t = id / B_, b = id % B_;
        #pragma unroll
        for (int n = 0; n < 8; ++n) {
            float v = (n == i1 || n == i2) ? p[n] : 0.f;
            cw[((size_t)(b * N_ + n)) * T_ + t] = v;
        }
    }
}

// ---------------- capacity: exact top-CAP rank per (b,n); builds inverse map ----------------
__global__ __launch_bounds__(256) void k_capacity(
        const float* __restrict__ cw, int* __restrict__ toks,
        float* __restrict__ wts, int* __restrict__ counts,
        int* __restrict__ ecnt, int* __restrict__ erow) {
    __shared__ float v[T_];
    __shared__ int keep[T_];
    int tid = threadIdx.x;
    int bn = blockIdx.x;
    int b = bn >> 3, n = bn & 7;
    if (tid < T_) v[tid] = cw[(size_t)bn * T_ + tid];
    __syncthreads();
    int kp = 0; float my = 0.f;
    if (tid < T_) {
        my = v[tid];
        int rank = 0;
        for (int t2 = 0; t2 < T_; ++t2) {
            float vt = v[t2];
            rank += (vt > my) || (vt == my && t2 < tid);
        }
        kp = (rank < CAP_) && (my > 0.f);
    }
    if (tid < T_) keep[tid] = kp;
    __syncthreads();
    if (tid < T_ && kp) {
        int slot = 0;
        for (int t2 = 0; t2 < T_; ++t2) slot += (t2 < tid) ? keep[t2] : 0;
        toks[bn * CAP_ + slot] = tid;
        wts[bn * CAP_ + slot] = my;
        if (ecnt) {
            int orow = tid * B_ + b;
            int pos = atomicAdd(&ecnt[orow], 1);
            erow[orow * 2 + pos] = n * ME_ + b * CAP_ + slot;
        }
    }
    if (tid == 0) {
        int tot = 0;
        for (int t2 = 0; t2 < T_; ++t2) tot += keep[t2];
        counts[bn] = tot;
    }
}

// ---------------- gather x rows -> Xg [MT_][768] bf16, pre-swizzled, zero-padded ----------------
__global__ __launch_bounds__(256) void k_gather(
        const float* __restrict__ x, const int* __restrict__ toks,
        const int* __restrict__ counts, unsigned short* __restrict__ Xg) {
    int gi = blockIdx.x * 256 + threadIdx.x;
    int R = gi / 96, c = gi - R * 96;
    int e = R / ME_, re = R - e * ME_;
    uint4 val = make_uint4(0u, 0u, 0u, 0u);
    if (re < MR_) {
        int g = re / CAP_, slot = re - g * CAP_;
        int bn = g * N_ + e;
        if (slot < counts[bn]) {
            int t = toks[bn * CAP_ + slot];
            const float* xp = x + ((size_t)t * B_ + g) * F_ + c * 8;
            float4 v0 = *(const float4*)xp;
            float4 v1 = *(const float4*)(xp + 4);
            val.x = f2bf(v0.x) | ((unsigned)f2bf(v0.y) << 16);
            val.y = f2bf(v0.z) | ((unsigned)f2bf(v0.w) << 16);
            val.z = f2bf(v1.x) | ((unsigned)f2bf(v1.y) << 16);
            val.w = f2bf(v1.z) | ((unsigned)f2bf(v1.w) << 16);
        }
    }
    int w = (c * 16) & 127;
    char* dst = (char*)Xg + (size_t)R * 1536 + (c >> 3) * 128 + (w ^ ((R & 7) << 4));
    *(uint4*)dst = val;
}

// ---------------- GEMM1 (templated): Hg cols = relu(W1T . Xg^T + b1) ----------------
template<int NJT, int HSTRIDE>
__global__ __launch_bounds__(256) void k_gemm1(
        const unsigned short* __restrict__ W1T, const unsigned short* __restrict__ Xg,
        const float* __restrict__ b1, unsigned short* __restrict__ Hg,
        int jofs, int nblk) {
    __shared__ char ldsA[2][16384];
    __shared__ char ldsB[2][16384];
    int swzb = xcd_swz(blockIdx.x, nblk);
    const int per_e = 25 * NJT;
    int e = swzb / per_e;
    int rem = swzb - e * per_e;
    int mt = rem / NJT, jtl = rem % NJT;
    int jt = jofs + jtl;
    int tid = threadIdx.x, lane = tid & 63, wid = tid >> 6;
    int lr8 = lane >> 3, sl = (lane & 7) << 4;
    const char* Ab = (const char*)W1T + ((size_t)e * H_ + (size_t)jt * 128) * (F_ * 2);
    const char* Bb = (const char*)Xg + ((size_t)e * ME_ + (size_t)mt * 128) * (F_ * 2);
    f32x4 acc[4][4] = {};
    int swz = (lane & 7) << 4;
    int q16 = (lane >> 4) << 4;

    auto stage = [&](int buf, int it) {
        int kb = it << 7;
        #pragma unroll
        for (int i = 0; i < 4; ++i) {
            int lr = wid * 32 + i * 8 + lr8;
            GLL16(Ab + (size_t)lr * 1536 + kb + sl, ldsA[buf] + (wid * 32 + i * 8) * 128);
            GLL16(Bb + (size_t)lr * 1536 + kb + sl, ldsB[buf] + (wid * 32 + i * 8) * 128);
        }
    };

    stage(0, 0);
    __syncthreads();
    int cur = 0;
    #pragma unroll 1
    for (int it = 0; it < 12; ++it) {
        if (it < 11) stage(cur ^ 1, it + 1);
        const char* la = ldsA[cur] + ((wid & 1) * 64) * 128;
        const char* lb = ldsB[cur] + ((wid >> 1) * 64) * 128;
        #pragma unroll
        for (int ks = 0; ks < 2; ++ks) {
            bf16x8 af[4], bfr[4];
            int kk = (ks * 64 + q16) ^ swz;
            #pragma unroll
            for (int t = 0; t < 4; ++t) {
                int ro = (16 * t + (lane & 15)) * 128;
                af[t]  = *(const bf16x8*)(la + ro + kk);
                bfr[t] = *(const bf16x8*)(lb + ro + kk);
            }
            #pragma unroll
            for (int ti = 0; ti < 4; ++ti)
                #pragma unroll
                for (int tm = 0; tm < 4; ++tm)
                    acc[ti][tm] = __builtin_amdgcn_mfma_f32_16x16x32_bf16(af[ti], bfr[tm], acc[ti][tm], 0, 0, 0);
        }
        __syncthreads();
        cur ^= 1;
    }
    char* tile = &ldsA[0][0];
    int jl0 = (wid & 1) * 64;
    int ml0 = (wid >> 1) * 64;
    const float* b1p = b1 + (size_t)e * H_ + (size_t)jt * 128;
    #pragma unroll
    for (int tj = 0; tj < 4; ++tj) {
        int jc = jl0 + 16 * tj + ((lane >> 4) << 2);
        float bb0 = b1p[jc], bb1 = b1p[jc + 1], bb2 = b1p[jc + 2], bb3 = b1p[jc + 3];
        #pragma unroll
        for (int tm = 0; tm < 4; ++tm) {
            int m = ml0 + 16 * tm + (lane & 15);
            f32x4 a = acc[tj][tm];
            unsigned int u0 = f2bf(fmaxf(a[0] + bb0, 0.f)) | ((unsigned)f2bf(fmaxf(a[1] + bb1, 0.f)) << 16);
            unsigned int u1 = f2bf(fmaxf(a[2] + bb2, 0.f)) | ((unsigned)f2bf(fmaxf(a[3] + bb3, 0.f)) << 16);
            int bcol = jc * 2;
            int w = bcol & 127;
            *(uint2*)(tile + m * 256 + (bcol & ~127) + (w ^ ((m & 7) << 4))) = make_uint2(u0, u1);
        }
    }
    __syncthreads();
    char* Hrow = (char*)Hg + ((size_t)e * ME_ + (size_t)mt * 128) * HSTRIDE + (size_t)jtl * 256;
    #pragma unroll
    for (int i = 0; i < 8; ++i) {
        int idx = tid + i * 256;
        int r = idx >> 4, c = (idx & 15) << 4;
        *(uint4*)(Hrow + (size_t)r * HSTRIDE + c) = *(const uint4*)(tile + r * 256 + c);
    }
}

// ---------------- GEMM2 (templated): Og (+)= fw * (W2T[K-slice] . Hg^T) (+fw*b2 when kofsB==0) ----------------
template<int KITERS, int BSTRIDE>
__global__ __launch_bounds__(256) void k_gemm2(
        const unsigned short* __restrict__ W2T, const unsigned short* __restrict__ Hg,
        const float* __restrict__ b2, const float* __restrict__ wts,
        const int* __restrict__ counts, unsigned short* __restrict__ Og,
        int kofsB, int nblk) {
    __shared__ char ldsA[2][16384];
    __shared__ char ldsB[2][16384];
    int swzb = xcd_swz(blockIdx.x, nblk);
    int e = swzb / 150;
    int rem = swzb - e * 150;
    int mt = rem / 6, ft = rem % 6;
    int tid = threadIdx.x, lane = tid & 63, wid = tid >> 6;
    int lr8 = lane >> 3, sl = (lane & 7) << 4;
    const char* Ab = (const char*)W2T + ((size_t)e * F_ + (size_t)ft * 128) * (H_ * 2) + kofsB;
    const char* Bb = (const char*)Hg + ((size_t)e * ME_ + (size_t)mt * 128) * BSTRIDE;
    f32x4 acc[4][4] = {};
    int swz = (lane & 7) << 4;
    int q16 = (lane >> 4) << 4;

    auto stage = [&](int buf, int it) {
        int kb = it << 7;
        #pragma unroll
        for (int i = 0; i < 4; ++i) {
            int lr = wid * 32 + i * 8 + lr8;
            GLL16(Ab + (size_t)lr * 6144 + kb + sl, ldsA[buf] + (wid * 32 + i * 8) * 128);
            GLL16(Bb + (size_t)lr * BSTRIDE + kb + sl, ldsB[buf] + (wid * 32 + i * 8) * 128);
        }
    };

    stage(0, 0);
    __syncthreads();
    int cur = 0;
    #pragma unroll 1
    for (int it = 0; it < KITERS; ++it) {
        if (it < KITERS - 1) stage(cur ^ 1, it + 1);
        const char* la = ldsA[cur] + ((wid & 1) * 64) * 128;
        const char* lb = ldsB[cur] + ((wid >> 1) * 64) * 128;
        #pragma unroll
        for (int ks = 0; ks < 2; ++ks) {
            bf16x8 af[4], bfr[4];
            int kk = (ks * 64 + q16) ^ swz;
            #pragma unroll
            for (int t = 0; t < 4; ++t) {
                int ro = (16 * t + (lane & 15)) * 128;
                af[t]  = *(const bf16x8*)(la + ro + kk);
                bfr[t] = *(const bf16x8*)(lb + ro + kk);
            }
            #pragma unroll
            for (int ti = 0; ti < 4; ++ti)
                #pragma unroll
                for (int tm = 0; tm < 4; ++tm)
                    acc[ti][tm] = __builtin_amdgcn_mfma_f32_16x16x32_bf16(af[ti], bfr[tm], acc[ti][tm], 0, 0, 0);
        }
        __syncthreads();
        cur ^= 1;
    }
    char* tile = &ldsA[0][0];
    int fl0 = (wid & 1) * 64;
    int ml0 = (wid >> 1) * 64;
    const float* b2p = b2 + (size_t)e * F_ + (size_t)ft * 128;
    float fwv[4];
    #pragma unroll
    for (int tm = 0; tm < 4; ++tm) {
        int mloc = ml0 + 16 * tm + (lane & 15);
        int re = mt * 128 + mloc;
        float fw = 0.f;
        if (re < MR_) {
            int g = re / CAP_;
            int slot = re - g * CAP_;
            int bn = g * N_ + e;
            if (slot < counts[bn]) fw = wts[bn * CAP_ + slot];
        }
        fwv[tm] = fw;
    }
    int p0 = (kofsB == 0);
    #pragma unroll
    for (int tf = 0; tf < 4; ++tf) {
        int fc = fl0 + 16 * tf + ((lane >> 4) << 2);
        float c0 = 0.f, c1 = 0.f, c2 = 0.f, c3 = 0.f;
        if (p0) { c0 = b2p[fc]; c1 = b2p[fc + 1]; c2 = b2p[fc + 2]; c3 = b2p[fc + 3]; }
        #pragma unroll
        for (int tm = 0; tm < 4; ++tm) {
            int mloc = ml0 + 16 * tm + (lane & 15);
            f32x4 a = acc[tf][tm];
            float fw = fwv[tm];
            unsigned int u0 = f2bf(fw * (a[0] + c0)) | ((unsigned)f2bf(fw * (a[1] + c1)) << 16);
            unsigned int u1 = f2bf(fw * (a[2] + c2)) | ((unsigned)f2bf(fw * (a[3] + c3)) << 16);
            int bcol = fc * 2;
            int w = bcol & 127;
            *(uint2*)(tile + mloc * 256 + (bcol & ~127) + (w ^ ((mloc & 7) << 4))) = make_uint2(u0, u1);
        }
    }
    __syncthreads();
    char* Orow = (char*)Og + ((size_t)e * ME_ + (size_t)mt * 128) * (F_ * 2) + (size_t)ft * 256;
    if (KITERS == 48 || p0) {
        #pragma unroll
        for (int i = 0; i < 8; ++i) {
            int idx = tid + i * 256;
            int r = idx >> 4, c = (idx & 15) << 4;
            const char* src = tile + r * 256 + (c & ~127) + ((c & 127) ^ ((r & 7) << 4));
            *(uint4*)(Orow + (size_t)r * (F_ * 2) + c) = *(const uint4*)src;
        }
    } else {
        #pragma unroll
        for (int i = 0; i < 8; ++i) {
            int idx = tid + i * 256;
            int r = idx >> 4, c = (idx & 15) << 4;
            const char* src = tile + r * 256 + (c & ~127) + ((c & 127) ^ ((r & 7) << 4));
            uint4 nw = *(const uint4*)src;
            uint4* dst = (uint4*)(Orow + (size_t)r * (F_ * 2) + c);
            uint4 old = *dst;
            uint4 res;
            res.x = add2bf(old.x, nw.x);
            res.y = add2bf(old.y, nw.y);
            res.z = add2bf(old.z, nw.z);
            res.w = add2bf(old.w, nw.w);
            *dst = res;
        }
    }
}

// ---------------- combine: out[t,b,:] = sum(og entries) - x ----------------
__global__ __launch_bounds__(256) void k_combine(
        const float* __restrict__ x, const unsigned short* __restrict__ Og,
        const int* __restrict__ ecnt, const int* __restrict__ erow,
        float* __restrict__ out) {
    int idx = blockIdx.x * 256 + threadIdx.x;
    int row = idx / 192, c4 = idx - row * 192;
    float4 s = make_float4(0.f, 0.f, 0.f, 0.f);
    int c = ecnt[row];
    if (c > 0) {
        ushort4 u = *(const ushort4*)(Og + (size_t)erow[row * 2] * F_ + c4 * 4);
        s.x += bf2f(u.x); s.y += bf2f(u.y); s.z += bf2f(u.z); s.w += bf2f(u.w);
    }
    if (c > 1) {
        ushort4 u = *(const ushort4*)(Og + (size_t)erow[row * 2 + 1] * F_ + c4 * 4);
        s.x += bf2f(u.x); s.y += bf2f(u.y); s.z += bf2f(u.z); s.w += bf2f(u.w);
    }
    float4 xv = ((const float4*)x)[idx];
    ((float4*)out)[idx] = make_float4(s.x - xv.x, s.y - xv.y, s.z - xv.z, s.w - xv.w);
}

// ================= round-1 fallback kernels (tiny ws only) =================
__global__ __launch_bounds__(HCF_) void k_fc1(
        const float* __restrict__ x, const float* __restrict__ W1,
        const float* __restrict__ b1, const int* __restrict__ toks,
        const int* __restrict__ counts, __hip_bfloat16* __restrict__ h, int pass) {
    __shared__ float xs[25][F_];
    int tid = threadIdx.x;
    int bn = blockIdx.x >> 1;
    int half = blockIdx.x & 1;
    int r0 = half * 25;
    int b = bn >> 3, n = bn & 7;
    int c = counts[bn];
    for (int idx = tid; idx < 25 * (F_/4); idx += HCF_) {
        int r = idx / (F_/4), k4 = idx % (F_/4);
        int gr = r0 + r;
        float4 val = make_float4(0.f, 0.f, 0.f, 0.f);
        if (gr < c) {
            int t = toks[bn * CAP_ + gr];
            val = ((const float4*)(x + ((size_t)(t * B_ + b)) * F_))[k4];
        }
        ((float4*)&xs[r][0])[k4] = val;
    }
    __syncthreads();
    int j = pass * HCF_ + tid;
    const float* w1p = W1 + (size_t)n * F_ * H_ + j;
    float bias = b1[n * H_ + j];
    float acc[25];
    #pragma unroll
    for (int r = 0; r < 25; ++r) acc[r] = bias;
    const float4* xsv = (const float4*)&xs[0][0];
    for (int k4 = 0; k4 < F_/4; ++k4) {
        float w0 = w1p[(size_t)(4*k4+0) * H_];
        float w1v = w1p[(size_t)(4*k4+1) * H_];
        float w2v = w1p[(size_t)(4*k4+2) * H_];
        float w3v = w1p[(size_t)(4*k4+3) * H_];
        #pragma unroll
        for (int r = 0; r < 25; ++r) {
            float4 xv = xsv[r * (F_/4) + k4];
            acc[r] += xv.x*w0 + xv.y*w1v + xv.z*w2v + xv.w*w3v;
        }
    }
    __hip_bfloat16* hp = h + ((size_t)bn * CAP_ + r0) * HCF_ + tid;
    #pragma unroll
    for (int r = 0; r < 25; ++r) {
        int gr = r0 + r;
        if (gr < CAP_) hp[(size_t)r * HCF_] = __float2bfloat16(fmaxf(acc[r], 0.f));
    }
}

__global__ __launch_bounds__(768) void k_fc2(
        const float* __restrict__ W2, const float* __restrict__ b2,
        const int* __restrict__ toks, const float* __restrict__ wts,
        const int* __restrict__ counts, const __hip_bfloat16* __restrict__ h,
        float* __restrict__ out, int pass) {
    __shared__ float hs[CAP_][HCF_];
    int tid = threadIdx.x;
    int bn = blockIdx.x;
    int c = counts[bn];
    if (c == 0) return;
    int b = bn >> 3, n = bn & 7;
    const ushort4* hv = (const ushort4*)(h + (size_t)bn * CAP_ * HCF_);
    for (int idx = tid; idx < CAP_ * (HCF_/4); idx += 768) {
        ushort4 u = hv[idx];
        float4 fv;
        fv.x = __bfloat162float(*(const __hip_bfloat16*)&u.x);
        fv.y = __bfloat162float(*(const __hip_bfloat16*)&u.y);
        fv.z = __bfloat162float(*(const __hip_bfloat16*)&u.z);
        fv.w = __bfloat162float(*(const __hip_bfloat16*)&u.w);
        ((float4*)&hs[0][0])[idx] = fv;
    }
    __syncthreads();
    int f = tid;
    const float* w2p = W2 + (size_t)n * H_ * F_ + (size_t)(pass * HCF_) * F_ + f;
    float acc[CAP_];
    #pragma unroll
    for (int r = 0; r < CAP_; ++r) acc[r] = 0.f;
    for (int j4 = 0; j4 < HCF_/4; ++j4) {
        float w0 = w2p[(size_t)(4*j4+0) * F_];
        float w1v = w2p[(size_t)(4*j4+1) * F_];
        float w2v = w2p[(size_t)(4*j4+2) * F_];
        float w3v = w2p[(size_t)(4*j4+3) * F_];
        #pragma unroll
        for (int r = 0; r < CAP_; ++r) {
            float4 hh = ((const float4*)&hs[r][0])[j4];
            acc[r] += hh.x*w0 + hh.y*w1v + hh.z*w2v + hh.w*w3v;
        }
    }
    float bias = (pass == 0) ? b2[n * F_ + f] : 0.f;
    #pragma unroll
    for (int r = 0; r < CAP_; ++r) {
        if (r < c) {
            int t = toks[bn * CAP_ + r];
            float fw = wts[bn * CAP_ + r];
            atomicAdd(&out[((size_t)(t * B_ + b)) * F_ + f], fw * (acc[r] + bias));
        }
    }
}

extern "C" void kernel_launch(void* const* d_in, const int* in_sizes, int n_in,
                              void* d_out, int out_size, void* d_ws, size_t ws_size,
                              hipStream_t stream) {
    const float* x   = (const float*)d_in[0];
    const float* Wg1 = (const float*)d_in[1];
    const float* bg1 = (const float*)d_in[2];
    const float* Wg2 = (const float*)d_in[3];
    const float* bg2 = (const float*)d_in[4];
    const float* W1  = (const float*)d_in[5];
    const float* b1  = (const float*)d_in[6];
    const float* W2  = (const float*)d_in[7];
    const float* b2  = (const float*)d_in[8];
    float* out = (float*)d_out;

    // ws layout (Og aliases Xg in tier A; separate in tier B)
    size_t oW1T  = 0;
    size_t oW2T  = oW1T + (size_t)N_ * H_ * F_ * 2;     // 37.75 MB
    size_t oXg   = oW2T + (size_t)N_ * H_ * F_ * 2;     // 75.5 MB
    size_t oCw   = oXg  + (size_t)MT_ * F_ * 2;         // +39.3 MB
    size_t oWts  = oCw  + (size_t)NBN_ * T_ * 4;
    size_t oTok  = oWts + (size_t)NBN_ * CAP_ * 4;
    size_t oCnt  = oTok + (size_t)NBN_ * CAP_ * 4;
    size_t oEcnt = oCnt + (size_t)NBN_ * 4;
    size_t oErow = oEcnt + (size_t)TB_ * 4;
    size_t oHg   = oErow + (size_t)TB_ * 8;             // ~115.6 MB
    size_t needA = oHg + (size_t)MT_ * H_ * 2;          // ~272.9 MB (full Hg; Og aliases Xg)
    size_t oOgB  = oHg + (size_t)MT_ * HP_ * 2;         // tier-B Og after Hg quarter
    size_t needB = oOgB + (size_t)MT_ * F_ * 2;         // ~194.2 MB

    if (ws_size >= needB) {
        unsigned short* W1T = (unsigned short*)((char*)d_ws + oW1T);
        unsigned short* W2T = (unsigned short*)((char*)d_ws + oW2T);
        unsigned short* Xg  = (unsigned short*)((char*)d_ws + oXg);
        unsigned short* Hg  = (unsigned short*)((char*)d_ws + oHg);
        float* gs_part = (float*)((char*)d_ws + oHg);   // aliases Hg; dead after k_gate2
        float* cw   = (float*)((char*)d_ws + oCw);
        float* wts  = (float*)((char*)d_ws + oWts);
        int* toks   = (int*)((char*)d_ws + oTok);
        int* counts = (int*)((char*)d_ws + oCnt);
        int* ecnt   = (int*)((char*)d_ws + oEcnt);
        int* erow   = (int*)((char*)d_ws + oErow);

        int tierA = (ws_size >= needA);
        unsigned short* Og = tierA ? Xg                     // tier A: Xg dead after single gemm1
                                   : (unsigned short*)((char*)d_ws + oOgB);

        // fused: gate1 + repack(W1) + repack(W2) — independent, co-scheduled
        k_fused<<<G1B_ + 2 * RPB_, 256, 0, stream>>>(x, Wg1, gs_part, W1, W1T, W2, W2T);
        k_gate2<<<TB_ / 32, 256, 0, stream>>>(gs_part, bg1, Wg2, bg2, cw, ecnt);
        k_capacity<<<NBN_, 256, 0, stream>>>(cw, toks, wts, counts, ecnt, erow);
        k_gather<<<(MT_ * 96) / 256, 256, 0, stream>>>(x, toks, counts, Xg);
        if (tierA) {
            k_gemm1<24, H_ * 2><<<4800, 256, 0, stream>>>(W1T, Xg, b1, Hg, 0, 4800);
            k_gemm2<48, H_ * 2><<<1200, 256, 0, stream>>>(W2T, Hg, b2, wts, counts, Og, 0, 1200);
        } else {
            for (int p = 0; p < 4; ++p) {
                k_gemm1<6, HP_ * 2><<<1200, 256, 0, stream>>>(W1T, Xg, b1, Hg, p * 6, 1200);
                k_gemm2<12, HP_ * 2><<<1200, 256, 0, stream>>>(W2T, Hg, b2, wts, counts, Og, p * HP_ * 2, 1200);
            }
        }
        k_combine<<<(TB_ * 192) / 256, 256, 0, stream>>>(x, Og, ecnt, erow, out);
    } else {
        // round-1 fallback (~20 MB ws)
        __hip_bfloat16* h = (__hip_bfloat16*)d_ws;
        float* cw  = (float*)((char*)d_ws + (size_t)NBN_ * CAP_ * HCF_ * 2);
        float* wts = cw + (size_t)NBN_ * T_;
        int* toks  = (int*)(wts + NBN_ * CAP_);
        int* counts = toks + NBN_ * CAP_;
        k_init_out<<<(TB_ * F_) / 1024, 256, 0, stream>>>(x, out);
        k_gate<<<TB_ / 8, 256, 0, stream>>>(x, Wg1, bg1, Wg2, bg2, cw, nullptr);
        k_capacity<<<NBN_, 256, 0, stream>>>(cw, toks, wts, counts, nullptr, nullptr);
        for (int p = 0; p < NPF_; ++p) {
            k_fc1<<<NBN_ * 2, HCF_, 0, stream>>>(x, W1, b1, toks, counts, h, p);
            k_fc2<<<NBN_, 768, 0, stream>>>(W2, b2, toks, wts, counts, h, out, p);
        }
    }
}

// Round 18
// 454.953 us; speedup vs baseline: 1.1380x; 1.0209x over previous
//
#include <hip/hip_runtime.h>
#include <hip/hip_bf16.h>
#include <math.h>
#include <stdint.h>

#define T_ 197
#define B_ 64
#define F_ 768
#define N_ 8
#define CAP_ 49
#define H_ 3072
#define G_ 192
#define TB_ (T_*B_)       // 12608
#define NBN_ (B_*N_)      // 512
#define ME_ 3200          // padded rows per expert (25 * 128)
#define MR_ 3136          // real rows per expert (64 * 49)
#define MT_ 25600         // total padded rows
#define KH_ 4             // gate1 K-split
#define HP_ 768           // tier-B GEMM H-pass chunk
#define HCF_ 384          // fallback (round-1) H chunk
#define NPF_ 8
#define G1B_ (197 * KH_)  // 788 gate1 blocks
#define RPB_ 4608         // repack blocks per weight

using bf16x8 = __attribute__((ext_vector_type(8))) short;
using f32x4  = __attribute__((ext_vector_type(4))) float;

__device__ __forceinline__ unsigned short f2bf(float v) {
    __hip_bfloat16 h = __float2bfloat16(v);
    return __builtin_bit_cast(unsigned short, h);
}
__device__ __forceinline__ float bf2f(unsigned short u) {
    unsigned int w = ((unsigned int)u) << 16;
    return __builtin_bit_cast(float, w);
}
__device__ __forceinline__ unsigned int add2bf(unsigned int a, unsigned int b) {
    float al = bf2f((unsigned short)(a & 0xffff)), ah = bf2f((unsigned short)(a >> 16));
    float bl = bf2f((unsigned short)(b & 0xffff)), bh = bf2f((unsigned short)(b >> 16));
    return (unsigned int)f2bf(al + bl) | ((unsigned int)f2bf(ah + bh) << 16);
}

// async global->LDS, 16B per lane; LDS dest = wave-uniform base + lane*16
#define GLL16(g, l) __builtin_amdgcn_global_load_lds( \
    (const __attribute__((address_space(1))) unsigned int*)(uintptr_t)(g), \
    (__attribute__((address_space(3))) unsigned int*)(uintptr_t)(l), 16, 0, 0)

// m204 bijective XCD swizzle
__device__ __forceinline__ int xcd_swz(int bid, int nblk) {
    int q = nblk >> 3, r = nblk & 7;
    int xcd = bid & 7, idx = bid >> 3;
    int base = (xcd < r) ? xcd * (q + 1) : r * (q + 1) + (xcd - r) * q;
    return base + idx;
}

// ---------------- out = -x (fallback path only) ----------------
__global__ void k_init_out(const float* __restrict__ x, float* __restrict__ out) {
    int i = blockIdx.x * blockDim.x + threadIdx.x;
    const float4* xv = (const float4*)x;
    float4* ov = (float4*)out;
    float4 v = xv[i];
    ov[i] = make_float4(-v.x, -v.y, -v.z, -v.w);
}

// ---------------- gate1 body (R7-v3 loop + coalesced LDS-transpose epilogue) ----------------
__device__ __forceinline__ void gate1_body(int bid, char* ldsraw,
        const float* __restrict__ x, const float* __restrict__ Wg1,
        float* __restrict__ gs_part) {
    float (*xs)[68]  = (float(*)[68])ldsraw;                    // 32x68
    float (*wt)[200] = (float(*)[200])(ldsraw + 32 * 68 * 4);   // 32x200
    int bm = bid % 197, kh = bid / 197;
    int m0 = bm * 64, k0 = kh * (F_ / KH_);
    int tid = threadIdx.x, lane = tid & 63, wid = tid >> 6;
    int mg = lane & 15;
    int ng = (lane >> 4) + 4 * wid;
    f32x4 acc[4][3] = {};

    int xr = tid >> 3, xc = tid & 7;
    float4 xreg0, xreg1;
    float4 wreg[6];

    auto loadRegs = [&](int t) {
        int kb = k0 + t * 32;
        xreg0 = *(const float4*)(x + (size_t)(m0 + xr) * F_ + kb + xc * 4);
        xreg1 = *(const float4*)(x + (size_t)(m0 + xr + 32) * F_ + kb + xc * 4);
        #pragma unroll
        for (int i = 0; i < 6; ++i) {
            int idx = tid + i * 256;
            int kr = idx / 48, nc = idx % 48;
            wreg[i] = *(const float4*)(Wg1 + (size_t)(kb + kr) * G_ + nc * 4);
        }
    };
    auto writeLDS = [&]() {
        xs[xc * 4 + 0][xr] = xreg0.x;  xs[xc * 4 + 1][xr] = xreg0.y;
        xs[xc * 4 + 2][xr] = xreg0.z;  xs[xc * 4 + 3][xr] = xreg0.w;
        xs[xc * 4 + 0][xr + 32] = xreg1.x;  xs[xc * 4 + 1][xr + 32] = xreg1.y;
        xs[xc * 4 + 2][xr + 32] = xreg1.z;  xs[xc * 4 + 3][xr + 32] = xreg1.w;
        #pragma unroll
        for (int i = 0; i < 6; ++i) {
            int idx = tid + i * 256;
            int kr = idx / 48, nc = idx % 48;
            *(float4*)&wt[kr][nc * 4] = wreg[i];
        }
    };

    loadRegs(0);
    for (int t = 0; t < 6; ++t) {
        __syncthreads();
        writeLDS();
        __syncthreads();
        if (t < 5) loadRegs(t + 1);
        #pragma unroll
        for (int k = 0; k < 32; ++k) {
            float4 av = *(const float4*)&xs[k][mg * 4];
            f32x4 b0 = *(const f32x4*)&wt[k][ng * 12];
            f32x4 b1 = *(const f32x4*)&wt[k][ng * 12 + 4];
            f32x4 b2 = *(const f32x4*)&wt[k][ng * 12 + 8];
            float am[4] = {av.x, av.y, av.z, av.w};
            #pragma unroll
            for (int mi = 0; mi < 4; ++mi) {
                acc[mi][0] += b0 * am[mi];
                acc[mi][1] += b1 * am[mi];
                acc[mi][2] += b2 * am[mi];
            }
        }
    }
    // coalesced epilogue: 2 chunks of 32 rows via LDS scratch (wt is dead)
    float* scratch = &wt[0][0];
    #pragma unroll
    for (int ch = 0; ch < 2; ++ch) {
        __syncthreads();
        if ((mg >> 3) == ch) {
            int lr = (mg & 7) * 4;
            #pragma unroll
            for (int mi = 0; mi < 4; ++mi) {
                float* rp = scratch + (size_t)(lr + mi) * 196 + ng * 12;
                *(f32x4*)(rp + 0) = acc[mi][0];
                *(f32x4*)(rp + 4) = acc[mi][1];
                *(f32x4*)(rp + 8) = acc[mi][2];
            }
        }
        __syncthreads();
        float* gp = gs_part + (size_t)kh * TB_ * G_ + (size_t)(m0 + ch * 32) * G_;
        #pragma unroll
        for (int i = 0; i < 6; ++i) {
            int idx = tid + i * 256;
            int r = idx / 48, c4 = idx % 48;
            *(float4*)(gp + (size_t)r * G_ + c4 * 4) =
                *(const float4*)(scratch + (size_t)r * 196 + c4 * 4);
        }
    }
}

// ---------------- repack body: W [E][K][J] fp32 -> WT [E][J][K] bf16, pre-swizzled ----------------
__device__ __forceinline__ void repack_body(int bid, char* ldsraw,
        const float* __restrict__ W, unsigned short* __restrict__ WT, int K, int J) {
    float (*tile)[65] = (float(*)[65])ldsraw;   // 64x65
    int nk = K >> 6, nj = J >> 6;
    int kt = bid % nk; bid /= nk;
    int jt = bid % nj; int e = bid / nj;
    int k0 = kt * 64, j0 = jt * 64;
    int tid = threadIdx.x;
    int jr = (tid & 15) << 2;
    int kr = tid >> 4;
    const float* src = W + ((size_t)e * K + k0) * J + j0;
    #pragma unroll
    for (int i = 0; i < 4; ++i) {
        float4 v = *(const float4*)(src + (size_t)(kr + 16 * i) * J + jr);
        *(float4*)&tile[kr + 16 * i][jr] = v;
    }
    __syncthreads();
    int c = tid & 7;
    int jrow = tid >> 3;
    #pragma unroll
    for (int i = 0; i < 2; ++i) {
        int j = jrow + 32 * i;
        float f[8];
        #pragma unroll
        for (int s = 0; s < 8; ++s) f[s] = tile[c * 8 + s][j];
        uint4 u;
        u.x = f2bf(f[0]) | ((unsigned)f2bf(f[1]) << 16);
        u.y = f2bf(f[2]) | ((unsigned)f2bf(f[3]) << 16);
        u.z = f2bf(f[4]) | ((unsigned)f2bf(f[5]) << 16);
        u.w = f2bf(f[6]) | ((unsigned)f2bf(f[7]) << 16);
        int jg = j0 + j;
        char* drow = (char*)WT + ((size_t)e * J + jg) * (size_t)K * 2 + (size_t)(k0 >> 6) * 128;
        *(uint4*)(drow + ((c << 4) ^ ((jg & 7) << 4))) = u;
    }
}

// ---------------- FUSED: gate1 blocks [0,788) + repack W1 [788,5396) + repack W2 [5396,10004) ----------------
__global__ __launch_bounds__(256) void k_fused(
        const float* __restrict__ x, const float* __restrict__ Wg1,
        float* __restrict__ gs_part,
        const float* __restrict__ W1, unsigned short* __restrict__ W1T,
        const float* __restrict__ W2, unsigned short* __restrict__ W2T) {
    __shared__ char lds[32 * 68 * 4 + 32 * 200 * 4];   // 34304 B (gate1 max)
    int bid = blockIdx.x;
    if (bid < G1B_) {
        gate1_body(bid, lds, x, Wg1, gs_part);
    } else if (bid < G1B_ + RPB_) {
        repack_body(bid - G1B_, lds, W1, W1T, F_, H_);
    } else {
        repack_body(bid - G1B_ - RPB_, lds, W2, W2T, H_, F_);
    }
}

// ---------------- gate layer2: reduce 4 partials + bias + relu -> logits -> softmax -> top2 ----------------
__global__ __launch_bounds__(256) void k_gate2(
        const float* __restrict__ gs_part, const float* __restrict__ bg1,
        const float* __restrict__ Wg2, const float* __restrict__ bg2,
        float* __restrict__ cw, int* __restrict__ ecnt) {
    __shared__ float gsh[32][200];
    __shared__ float wg2s[G_ * N_];
    __shared__ float lg[32][8];
    int tid = threadIdx.x;
    int id0 = blockIdx.x * 32;

    for (int i = tid; i < 32 * 48; i += 256) {
        int r = i / 48, c4 = i % 48;
        const float* p0 = gs_part + (size_t)(id0 + r) * G_ + c4 * 4;
        float4 g = *(const float4*)(bg1 + c4 * 4);
        float4 v = g;
        #pragma unroll
        for (int p = 0; p < KH_; ++p) {
            float4 a = *(const float4*)(p0 + (size_t)p * TB_ * G_);
            v.x += a.x; v.y += a.y; v.z += a.z; v.w += a.w;
        }
        v.x = fmaxf(v.x, 0.f); v.y = fmaxf(v.y, 0.f);
        v.z = fmaxf(v.z, 0.f); v.w = fmaxf(v.w, 0.f);
        ((float4*)&gsh[r][0])[c4] = v;
    }
    for (int i = tid; i < G_ * N_; i += 256) wg2s[i] = Wg2[i];
    __syncthreads();

    int tk = tid >> 3, n = tid & 7;
    float a = bg2[n];
    for (int k = 0; k < G_; ++k) a += gsh[tk][k] * wg2s[k * N_ + n];
    lg[tk][n] = a;
    __syncthreads();

    if (tid < 32) {
        int tk2 = tid;
        float p[8];
        float m = lg[tk2][0];
        #pragma unroll
        for (int nn = 1; nn < 8; ++nn) m = fmaxf(m, lg[tk2][nn]);
        float s = 0.f;
        #pragma unroll
        for (int nn = 0; nn < 8; ++nn) { p[nn] = expf(lg[tk2][nn] - m); s += p[nn]; }
        float inv = 1.f / s;
        #pragma unroll
        for (int nn = 0; nn < 8; ++nn) p[nn] *= inv;
        int i1 = 0; float v1 = p[0];
        #pragma unroll
        for (int nn = 1; nn < 8; ++nn) if (p[nn] > v1) { v1 = p[nn]; i1 = nn; }
        int i2 = -1; float v2 = -1.f;
        #pragma unroll
        for (int nn = 0; nn < 8; ++nn) if (nn != i1 && p[nn] > v2) { v2 = p[nn]; i2 = nn; }
        int id = id0 + tk2;
        int t = id / B_, b = id % B_;
        ecnt[id] = 0;
        #pragma unroll
        for (int nn = 0; nn < 8; ++nn) {
            float v = (nn == i1 || nn == i2) ? p[nn] : 0.f;
            cw[((size_t)(b * N_ + nn)) * T_ + t] = v;
        }
    }
}

// ---------------- gate (fallback path only) ----------------
__global__ __launch_bounds__(256) void k_gate(
        const float* __restrict__ x, const float* __restrict__ Wg1,
        const float* __restrict__ bg1, const float* __restrict__ Wg2,
        const float* __restrict__ bg2, float* __restrict__ cw,
        int* __restrict__ ecnt) {
    __shared__ float xsh[8][F_];
    __shared__ float gsl[8][G_];
    __shared__ float lg[8][N_];
    int tid = threadIdx.x;
    int id0 = blockIdx.x * 8;

    int gid = blockIdx.x * 256 + tid;
    if (gid < TB_ && ecnt) ecnt[gid] = 0;

    const float4* xv = (const float4*)(x + (size_t)id0 * F_);
    float4* xshv = (float4*)&xsh[0][0];
    for (int idx = tid; idx < 8 * (F_/4); idx += 256) xshv[idx] = xv[idx];
    __syncthreads();

    if (tid < G_) {
        float acc[8];
        float bb = bg1[tid];
        #pragma unroll
        for (int tk = 0; tk < 8; ++tk) acc[tk] = bb;
        for (int k = 0; k < F_; ++k) {
            float w = Wg1[k * G_ + tid];
            #pragma unroll
            for (int tk = 0; tk < 8; ++tk) acc[tk] += xsh[tk][k] * w;
        }
        #pragma unroll
        for (int tk = 0; tk < 8; ++tk) gsl[tk][tid] = fmaxf(acc[tk], 0.f);
    }
    __syncthreads();

    if (tid < 64) {
        int tk = tid >> 3, n = tid & 7;
        float acc = bg2[n];
        for (int k = 0; k < G_; ++k) acc += gsl[tk][k] * Wg2[k * N_ + n];
        lg[tk][n] = acc;
    }
    __syncthreads();

    if (tid < 8) {
        int tk = tid;
        float p[8];
        float m = lg[tk][0];
        #pragma unroll
        for (int n = 1; n < 8; ++n) m = fmaxf(m, lg[tk][n]);
        float s = 0.f;
        #pragma unroll
        for (int n = 0; n < 8; ++n) { p[n] = expf(lg[tk][n] - m); s += p[n]; }
        float inv = 1.f / s;
        #pragma unroll
        for (int n = 0; n < 8; ++n) p[n] *= inv;
        int i1 = 0; float v1 = p[0];
        #pragma unroll
        for (int n = 1; n < 8; ++n) if (p[n] > v1) { v1 = p[n]; i1 = n; }
        int i2 = -1; float v2 = -1.f;
        #pragma unroll
        for (int n = 0; n < 8; ++n) if (n != i1 && p[n] > v2) { v2 = p[n]; i2 = n; }
        int id = id0 + tk;
        int t = id / B_, b = id % B_;
        #pragma unroll
        for (int n = 0; n < 8; ++n) {
            float v = (n == i1 || n == i2) ? p[n] : 0.f;
            cw[((size_t)(b * N_ + n)) * T_ + t] = v;
        }
    }
}

// ---------------- capacity: exact top-CAP rank per (b,n); builds inverse map ----------------
__global__ __launch_bounds__(256) void k_capacity(
        const float* __restrict__ cw, int* __restrict__ toks,
        float* __restrict__ wts, int* __restrict__ counts,
        int* __restrict__ ecnt, int* __restrict__ erow) {
    __shared__ float v[T_];
    __shared__ int keep[T_];
    int tid = threadIdx.x;
    int bn = blockIdx.x;
    int b = bn >> 3, n = bn & 7;
    if (tid < T_) v[tid] = cw[(size_t)bn * T_ + tid];
    __syncthreads();
    int kp = 0; float my = 0.f;
    if (tid < T_) {
        my = v[tid];
        int rank = 0;
        for (int t2 = 0; t2 < T_; ++t2) {
            float vt = v[t2];
            rank += (vt > my) || (vt == my && t2 < tid);
        }
        kp = (rank < CAP_) && (my > 0.f);
    }
    if (tid < T_) keep[tid] = kp;
    __syncthreads();
    if (tid < T_ && kp) {
        int slot = 0;
        for (int t2 = 0; t2 < T_; ++t2) slot += (t2 < tid) ? keep[t2] : 0;
        toks[bn * CAP_ + slot] = tid;
        wts[bn * CAP_ + slot] = my;
        if (ecnt) {
            int orow = tid * B_ + b;
            int pos = atomicAdd(&ecnt[orow], 1);
            erow[orow * 2 + pos] = n * ME_ + b * CAP_ + slot;
        }
    }
    if (tid == 0) {
        int tot = 0;
        for (int t2 = 0; t2 < T_; ++t2) tot += keep[t2];
        counts[bn] = tot;
    }
}

// ---------------- gather x rows -> Xg [MT_][768] bf16, pre-swizzled, zero-padded ----------------
__global__ __launch_bounds__(256) void k_gather(
        const float* __restrict__ x, const int* __restrict__ toks,
        const int* __restrict__ counts, unsigned short* __restrict__ Xg) {
    int gi = blockIdx.x * 256 + threadIdx.x;
    int R = gi / 96, c = gi - R * 96;
    int e = R / ME_, re = R - e * ME_;
    uint4 val = make_uint4(0u, 0u, 0u, 0u);
    if (re < MR_) {
        int g = re / CAP_, slot = re - g * CAP_;
        int bn = g * N_ + e;
        if (slot < counts[bn]) {
            int t = toks[bn * CAP_ + slot];
            const float* xp = x + ((size_t)t * B_ + g) * F_ + c * 8;
            float4 v0 = *(const float4*)xp;
            float4 v1 = *(const float4*)(xp + 4);
            val.x = f2bf(v0.x) | ((unsigned)f2bf(v0.y) << 16);
            val.y = f2bf(v0.z) | ((unsigned)f2bf(v0.w) << 16);
            val.z = f2bf(v1.x) | ((unsigned)f2bf(v1.y) << 16);
            val.w = f2bf(v1.z) | ((unsigned)f2bf(v1.w) << 16);
        }
    }
    int w = (c * 16) & 127;
    char* dst = (char*)Xg + (size_t)R * 1536 + (c >> 3) * 128 + (w ^ ((R & 7) << 4));
    *(uint4*)dst = val;
}

// ---------------- GEMM1 (templated, dbuf): Hg cols = relu(W1T . Xg^T + b1) ----------------
template<int NJT, int HSTRIDE>
__global__ __launch_bounds__(256) void k_gemm1(
        const unsigned short* __restrict__ W1T, const unsigned short* __restrict__ Xg,
        const float* __restrict__ b1, unsigned short* __restrict__ Hg,
        int jofs, int nblk) {
    __shared__ char ldsA[2][16384];
    __shared__ char ldsB[2][16384];
    int swzb = xcd_swz(blockIdx.x, nblk);
    const int per_e = 25 * NJT;
    int e = swzb / per_e;
    int rem = swzb - e * per_e;
    int mt = rem / NJT, jtl = rem % NJT;
    int jt = jofs + jtl;
    int tid = threadIdx.x, lane = tid & 63, wid = tid >> 6;
    int lr8 = lane >> 3, sl = (lane & 7) << 4;
    const char* Ab = (const char*)W1T + ((size_t)e * H_ + (size_t)jt * 128) * (F_ * 2);
    const char* Bb = (const char*)Xg + ((size_t)e * ME_ + (size_t)mt * 128) * (F_ * 2);
    f32x4 acc[4][4] = {};
    int swz = (lane & 7) << 4;
    int q16 = (lane >> 4) << 4;

    auto stage = [&](int buf, int it) {
        int kb = it << 7;
        #pragma unroll
        for (int i = 0; i < 4; ++i) {
            int lr = wid * 32 + i * 8 + lr8;
            GLL16(Ab + (size_t)lr * 1536 + kb + sl, ldsA[buf] + (wid * 32 + i * 8) * 128);
            GLL16(Bb + (size_t)lr * 1536 + kb + sl, ldsB[buf] + (wid * 32 + i * 8) * 128);
        }
    };

    stage(0, 0);
    __syncthreads();
    int cur = 0;
    #pragma unroll 1
    for (int it = 0; it < 12; ++it) {
        if (it < 11) stage(cur ^ 1, it + 1);
        const char* la = ldsA[cur] + ((wid & 1) * 64) * 128;
        const char* lb = ldsB[cur] + ((wid >> 1) * 64) * 128;
        #pragma unroll
        for (int ks = 0; ks < 2; ++ks) {
            bf16x8 af[4], bfr[4];
            int kk = (ks * 64 + q16) ^ swz;
            #pragma unroll
            for (int t = 0; t < 4; ++t) {
                int ro = (16 * t + (lane & 15)) * 128;
                af[t]  = *(const bf16x8*)(la + ro + kk);
                bfr[t] = *(const bf16x8*)(lb + ro + kk);
            }
            #pragma unroll
            for (int ti = 0; ti < 4; ++ti)
                #pragma unroll
                for (int tm = 0; tm < 4; ++tm)
                    acc[ti][tm] = __builtin_amdgcn_mfma_f32_16x16x32_bf16(af[ti], bfr[tm], acc[ti][tm], 0, 0, 0);
        }
        __syncthreads();
        cur ^= 1;
    }
    char* tile = &ldsA[0][0];
    int jl0 = (wid & 1) * 64;
    int ml0 = (wid >> 1) * 64;
    const float* b1p = b1 + (size_t)e * H_ + (size_t)jt * 128;
    #pragma unroll
    for (int tj = 0; tj < 4; ++tj) {
        int jc = jl0 + 16 * tj + ((lane >> 4) << 2);
        float bb0 = b1p[jc], bb1 = b1p[jc + 1], bb2 = b1p[jc + 2], bb3 = b1p[jc + 3];
        #pragma unroll
        for (int tm = 0; tm < 4; ++tm) {
            int m = ml0 + 16 * tm + (lane & 15);
            f32x4 a = acc[tj][tm];
            unsigned int u0 = f2bf(fmaxf(a[0] + bb0, 0.f)) | ((unsigned)f2bf(fmaxf(a[1] + bb1, 0.f)) << 16);
            unsigned int u1 = f2bf(fmaxf(a[2] + bb2, 0.f)) | ((unsigned)f2bf(fmaxf(a[3] + bb3, 0.f)) << 16);
            int bcol = jc * 2;
            int w = bcol & 127;
            *(uint2*)(tile + m * 256 + (bcol & ~127) + (w ^ ((m & 7) << 4))) = make_uint2(u0, u1);
        }
    }
    __syncthreads();
    char* Hrow = (char*)Hg + ((size_t)e * ME_ + (size_t)mt * 128) * HSTRIDE + (size_t)jtl * 256;
    #pragma unroll
    for (int i = 0; i < 8; ++i) {
        int idx = tid + i * 256;
        int r = idx >> 4, c = (idx & 15) << 4;
        *(uint4*)(Hrow + (size_t)r * HSTRIDE + c) = *(const uint4*)(tile + r * 256 + c);
    }
}

// ---------------- GEMM2 (templated, SINGLE-buffer 32KB -> 5 blocks/CU, all 1200 resident) ----------------
template<int KITERS, int BSTRIDE>
__global__ __launch_bounds__(256) void k_gemm2(
        const unsigned short* __restrict__ W2T, const unsigned short* __restrict__ Hg,
        const float* __restrict__ b2, const float* __restrict__ wts,
        const int* __restrict__ counts, unsigned short* __restrict__ Og,
        int kofsB, int nblk) {
    __shared__ char lds[32768];                 // A @ 0 (16KB), B @ 16384 (16KB)
    char* ldsA = lds;
    char* ldsB = lds + 16384;
    int swzb = xcd_swz(blockIdx.x, nblk);
    int e = swzb / 150;
    int rem = swzb - e * 150;
    int mt = rem / 6, ft = rem % 6;
    int tid = threadIdx.x, lane = tid & 63, wid = tid >> 6;
    int lr8 = lane >> 3, sl = (lane & 7) << 4;
    const char* Ab = (const char*)W2T + ((size_t)e * F_ + (size_t)ft * 128) * (H_ * 2) + kofsB;
    const char* Bb = (const char*)Hg + ((size_t)e * ME_ + (size_t)mt * 128) * BSTRIDE;
    f32x4 acc[4][4] = {};
    int swz = (lane & 7) << 4;
    int q16 = (lane >> 4) << 4;

    #pragma unroll 1
    for (int it = 0; it < KITERS; ++it) {
        int kb = it << 7;
        #pragma unroll
        for (int i = 0; i < 4; ++i) {
            int lr = wid * 32 + i * 8 + lr8;
            GLL16(Ab + (size_t)lr * 6144 + kb + sl, ldsA + (wid * 32 + i * 8) * 128);
            GLL16(Bb + (size_t)lr * BSTRIDE + kb + sl, ldsB + (wid * 32 + i * 8) * 128);
        }
        __syncthreads();                        // drain vmcnt -> LDS ready
        const char* la = ldsA + ((wid & 1) * 64) * 128;
        const char* lb = ldsB + ((wid >> 1) * 64) * 128;
        #pragma unroll
        for (int ks = 0; ks < 2; ++ks) {
            bf16x8 af[4], bfr[4];
            int kk = (ks * 64 + q16) ^ swz;
            #pragma unroll
            for (int t = 0; t < 4; ++t) {
                int ro = (16 * t + (lane & 15)) * 128;
                af[t]  = *(const bf16x8*)(la + ro + kk);
                bfr[t] = *(const bf16x8*)(lb + ro + kk);
            }
            #pragma unroll
            for (int ti = 0; ti < 4; ++ti)
                #pragma unroll
                for (int tm = 0; tm < 4; ++tm)
                    acc[ti][tm] = __builtin_amdgcn_mfma_f32_16x16x32_bf16(af[ti], bfr[tm], acc[ti][tm], 0, 0, 0);
        }
        __syncthreads();                        // all reads done -> LDS reusable
    }
    char* tile = lds;                           // full 32KB epilogue tile
    int fl0 = (wid & 1) * 64;
    int ml0 = (wid >> 1) * 64;
    const float* b2p = b2 + (size_t)e * F_ + (size_t)ft * 128;
    float fwv[4];
    #pragma unroll
    for (int tm = 0; tm < 4; ++tm) {
        int mloc = ml0 + 16 * tm + (lane & 15);
        int re = mt * 128 + mloc;
        float fw = 0.f;
        if (re < MR_) {
            int g = re / CAP_;
            int slot = re - g * CAP_;
            int bn = g * N_ + e;
            if (slot < counts[bn]) fw = wts[bn * CAP_ + slot];
        }
        fwv[tm] = fw;
    }
    int p0 = (kofsB == 0);
    #pragma unroll
    for (int tf = 0; tf < 4; ++tf) {
        int fc = fl0 + 16 * tf + ((lane >> 4) << 2);
        float c0 = 0.f, c1 = 0.f, c2 = 0.f, c3 = 0.f;
        if (p0) { c0 = b2p[fc]; c1 = b2p[fc + 1]; c2 = b2p[fc + 2]; c3 = b2p[fc + 3]; }
        #pragma unroll
        for (int tm = 0; tm < 4; ++tm) {
            int mloc = ml0 + 16 * tm + (lane & 15);
            f32x4 a = acc[tf][tm];
            float fw = fwv[tm];
            unsigned int u0 = f2bf(fw * (a[0] + c0)) | ((unsigned)f2bf(fw * (a[1] + c1)) << 16);
            unsigned int u1 = f2bf(fw * (a[2] + c2)) | ((unsigned)f2bf(fw * (a[3] + c3)) << 16);
            int bcol = fc * 2;
            int w = bcol & 127;
            *(uint2*)(tile + mloc * 256 + (bcol & ~127) + (w ^ ((mloc & 7) << 4))) = make_uint2(u0, u1);
        }
    }
    __syncthreads();
    char* Orow = (char*)Og + ((size_t)e * ME_ + (size_t)mt * 128) * (F_ * 2) + (size_t)ft * 256;
    if (KITERS == 48 || p0) {
        #pragma unroll
        for (int i = 0; i < 8; ++i) {
            int idx = tid + i * 256;
            int r = idx >> 4, c = (idx & 15) << 4;
            const char* src = tile + r * 256 + (c & ~127) + ((c & 127) ^ ((r & 7) << 4));
            *(uint4*)(Orow + (size_t)r * (F_ * 2) + c) = *(const uint4*)src;
        }
    } else {
        #pragma unroll
        for (int i = 0; i < 8; ++i) {
            int idx = tid + i * 256;
            int r = idx >> 4, c = (idx & 15) << 4;
            const char* src = tile + r * 256 + (c & ~127) + ((c & 127) ^ ((r & 7) << 4));
            uint4 nw = *(const uint4*)src;
            uint4* dst = (uint4*)(Orow + (size_t)r * (F_ * 2) + c);
            uint4 old = *dst;
            uint4 res;
            res.x = add2bf(old.x, nw.x);
            res.y = add2bf(old.y, nw.y);
            res.z = add2bf(old.z, nw.z);
            res.w = add2bf(old.w, nw.w);
            *dst = res;
        }
    }
}

// ---------------- combine: out[t,b,:] = sum(og entries) - x ----------------
__global__ __launch_bounds__(256) void k_combine(
        const float* __restrict__ x, const unsigned short* __restrict__ Og,
        const int* __restrict__ ecnt, const int* __restrict__ erow,
        float* __restrict__ out) {
    int idx = blockIdx.x * 256 + threadIdx.x;
    int row = idx / 192, c4 = idx - row * 192;
    float4 s = make_float4(0.f, 0.f, 0.f, 0.f);
    int c = ecnt[row];
    if (c > 0) {
        ushort4 u = *(const ushort4*)(Og + (size_t)erow[row * 2] * F_ + c4 * 4);
        s.x += bf2f(u.x); s.y += bf2f(u.y); s.z += bf2f(u.z); s.w += bf2f(u.w);
    }
    if (c > 1) {
        ushort4 u = *(const ushort4*)(Og + (size_t)erow[row * 2 + 1] * F_ + c4 * 4);
        s.x += bf2f(u.x); s.y += bf2f(u.y); s.z += bf2f(u.z); s.w += bf2f(u.w);
    }
    float4 xv = ((const float4*)x)[idx];
    ((float4*)out)[idx] = make_float4(s.x - xv.x, s.y - xv.y, s.z - xv.z, s.w - xv.w);
}

// ================= round-1 fallback kernels (tiny ws only) =================
__global__ __launch_bounds__(HCF_) void k_fc1(
        const float* __restrict__ x, const float* __restrict__ W1,
        const float* __restrict__ b1, const int* __restrict__ toks,
        const int* __restrict__ counts, __hip_bfloat16* __restrict__ h, int pass) {
    __shared__ float xs[25][F_];
    int tid = threadIdx.x;
    int bn = blockIdx.x >> 1;
    int half = blockIdx.x & 1;
    int r0 = half * 25;
    int b = bn >> 3, n = bn & 7;
    int c = counts[bn];
    for (int idx = tid; idx < 25 * (F_/4); idx += HCF_) {
        int r = idx / (F_/4), k4 = idx % (F_/4);
        int gr = r0 + r;
        float4 val = make_float4(0.f, 0.f, 0.f, 0.f);
        if (gr < c) {
            int t = toks[bn * CAP_ + gr];
            val = ((const float4*)(x + ((size_t)(t * B_ + b)) * F_))[k4];
        }
        ((float4*)&xs[r][0])[k4] = val;
    }
    __syncthreads();
    int j = pass * HCF_ + tid;
    const float* w1p = W1 + (size_t)n * F_ * H_ + j;
    float bias = b1[n * H_ + j];
    float acc[25];
    #pragma unroll
    for (int r = 0; r < 25; ++r) acc[r] = bias;
    const float4* xsv = (const float4*)&xs[0][0];
    for (int k4 = 0; k4 < F_/4; ++k4) {
        float w0 = w1p[(size_t)(4*k4+0) * H_];
        float w1v = w1p[(size_t)(4*k4+1) * H_];
        float w2v = w1p[(size_t)(4*k4+2) * H_];
        float w3v = w1p[(size_t)(4*k4+3) * H_];
        #pragma unroll
        for (int r = 0; r < 25; ++r) {
            float4 xv = xsv[r * (F_/4) + k4];
            acc[r] += xv.x*w0 + xv.y*w1v + xv.z*w2v + xv.w*w3v;
        }
    }
    __hip_bfloat16* hp = h + ((size_t)bn * CAP_ + r0) * HCF_ + tid;
    #pragma unroll
    for (int r = 0; r < 25; ++r) {
        int gr = r0 + r;
        if (gr < CAP_) hp[(size_t)r * HCF_] = __float2bfloat16(fmaxf(acc[r], 0.f));
    }
}

__global__ __launch_bounds__(768) void k_fc2(
        const float* __restrict__ W2, const float* __restrict__ b2,
        const int* __restrict__ toks, const float* __restrict__ wts,
        const int* __restrict__ counts, const __hip_bfloat16* __restrict__ h,
        float* __restrict__ out, int pass) {
    __shared__ float hs[CAP_][HCF_];
    int tid = threadIdx.x;
    int bn = blockIdx.x;
    int c = counts[bn];
    if (c == 0) return;
    int b = bn >> 3, n = bn & 7;
    const ushort4* hv = (const ushort4*)(h + (size_t)bn * CAP_ * HCF_);
    for (int idx = tid; idx < CAP_ * (HCF_/4); idx += 768) {
        ushort4 u = hv[idx];
        float4 fv;
        fv.x = __bfloat162float(*(const __hip_bfloat16*)&u.x);
        fv.y = __bfloat162float(*(const __hip_bfloat16*)&u.y);
        fv.z = __bfloat162float(*(const __hip_bfloat16*)&u.z);
        fv.w = __bfloat162float(*(const __hip_bfloat16*)&u.w);
        ((float4*)&hs[0][0])[idx] = fv;
    }
    __syncthreads();
    int f = tid;
    const float* w2p = W2 + (size_t)n * H_ * F_ + (size_t)(pass * HCF_) * F_ + f;
    float acc[CAP_];
    #pragma unroll
    for (int r = 0; r < CAP_; ++r) acc[r] = 0.f;
    for (int j4 = 0; j4 < HCF_/4; ++j4) {
        float w0 = w2p[(size_t)(4*j4+0) * F_];
        float w1v = w2p[(size_t)(4*j4+1) * F_];
        float w2v = w2p[(size_t)(4*j4+2) * F_];
        float w3v = w2p[(size_t)(4*j4+3) * F_];
        #pragma unroll
        for (int r = 0; r < CAP_; ++r) {
            float4 hh = ((const float4*)&hs[r][0])[j4];
            acc[r] += hh.x*w0 + hh.y*w1v + hh.z*w2v + hh.w*w3v;
        }
    }
    float bias = (pass == 0) ? b2[n * F_ + f] : 0.f;
    #pragma unroll
    for (int r = 0; r < CAP_; ++r) {
        if (r < c) {
            int t = toks[bn * CAP_ + r];
            float fw = wts[bn * CAP_ + r];
            atomicAdd(&out[((size_t)(t * B_ + b)) * F_ + f], fw * (acc[r] + bias));
        }
    }
}

extern "C" void kernel_launch(void* const* d_in, const int* in_sizes, int n_in,
                              void* d_out, int out_size, void* d_ws, size_t ws_size,
                              hipStream_t stream) {
    const float* x   = (const float*)d_in[0];
    const float* Wg1 = (const float*)d_in[1];
    const float* bg1 = (const float*)d_in[2];
    const float* Wg2 = (const float*)d_in[3];
    const float* bg2 = (const float*)d_in[4];
    const float* W1  = (const float*)d_in[5];
    const float* b1  = (const float*)d_in[6];
    const float* W2  = (const float*)d_in[7];
    const float* b2  = (const float*)d_in[8];
    float* out = (float*)d_out;

    // ws layout (Og aliases Xg in tier A; separate in tier B)
    size_t oW1T  = 0;
    size_t oW2T  = oW1T + (size_t)N_ * H_ * F_ * 2;     // 37.75 MB
    size_t oXg   = oW2T + (size_t)N_ * H_ * F_ * 2;     // 75.5 MB
    size_t oCw   = oXg  + (size_t)MT_ * F_ * 2;         // +39.3 MB
    size_t oWts  = oCw  + (size_t)NBN_ * T_ * 4;
    size_t oTok  = oWts + (size_t)NBN_ * CAP_ * 4;
    size_t oCnt  = oTok + (size_t)NBN_ * CAP_ * 4;
    size_t oEcnt = oCnt + (size_t)NBN_ * 4;
    size_t oErow = oEcnt + (size_t)TB_ * 4;
    size_t oHg   = oErow + (size_t)TB_ * 8;             // ~115.6 MB
    size_t needA = oHg + (size_t)MT_ * H_ * 2;          // ~272.9 MB (full Hg; Og aliases Xg)
    size_t oOgB  = oHg + (size_t)MT_ * HP_ * 2;         // tier-B Og after Hg quarter
    size_t needB = oOgB + (size_t)MT_ * F_ * 2;         // ~194.2 MB

    if (ws_size >= needB) {
        unsigned short* W1T = (unsigned short*)((char*)d_ws + oW1T);
        unsigned short* W2T = (unsigned short*)((char*)d_ws + oW2T);
        unsigned short* Xg  = (unsigned short*)((char*)d_ws + oXg);
        unsigned short* Hg  = (unsigned short*)((char*)d_ws + oHg);
        float* gs_part = (float*)((char*)d_ws + oHg);   // aliases Hg; dead after k_gate2
        float* cw   = (float*)((char*)d_ws + oCw);
        float* wts  = (float*)((char*)d_ws + oWts);
        int* toks   = (int*)((char*)d_ws + oTok);
        int* counts = (int*)((char*)d_ws + oCnt);
        int* ecnt   = (int*)((char*)d_ws + oEcnt);
        int* erow   = (int*)((char*)d_ws + oErow);

        int tierA = (ws_size >= needA);
        unsigned short* Og = tierA ? Xg                     // tier A: Xg dead after single gemm1
                                   : (unsigned short*)((char*)d_ws + oOgB);

        // fused: gate1 + repack(W1) + repack(W2) — independent, co-scheduled
        k_fused<<<G1B_ + 2 * RPB_, 256, 0, stream>>>(x, Wg1, gs_part, W1, W1T, W2, W2T);
        k_gate2<<<TB_ / 32, 256, 0, stream>>>(gs_part, bg1, Wg2, bg2, cw, ecnt);
        k_capacity<<<NBN_, 256, 0, stream>>>(cw, toks, wts, counts, ecnt, erow);
        k_gather<<<(MT_ * 96) / 256, 256, 0, stream>>>(x, toks, counts, Xg);
        if (tierA) {
            k_gemm1<24, H_ * 2><<<4800, 256, 0, stream>>>(W1T, Xg, b1, Hg, 0, 4800);
            k_gemm2<48, H_ * 2><<<1200, 256, 0, stream>>>(W2T, Hg, b2, wts, counts, Og, 0, 1200);
        } else {
            for (int p = 0; p < 4; ++p) {
                k_gemm1<6, HP_ * 2><<<1200, 256, 0, stream>>>(W1T, Xg, b1, Hg, p * 6, 1200);
                k_gemm2<12, HP_ * 2><<<1200, 256, 0, stream>>>(W2T, Hg, b2, wts, counts, Og, p * HP_ * 2, 1200);
            }
        }
        k_combine<<<(TB_ * 192) / 256, 256, 0, stream>>>(x, Og, ecnt, erow, out);
    } else {
        // round-1 fallback (~20 MB ws)
        __hip_bfloat16* h = (__hip_bfloat16*)d_ws;
        float* cw  = (float*)((char*)d_ws + (size_t)NBN_ * CAP_ * HCF_ * 2);
        float* wts = cw + (size_t)NBN_ * T_;
        int* toks  = (int*)(wts + NBN_ * CAP_);
        int* counts = toks + NBN_ * CAP_;
        k_init_out<<<(TB_ * F_) / 1024, 256, 0, stream>>>(x, out);
        k_gate<<<TB_ / 8, 256, 0, stream>>>(x, Wg1, bg1, Wg2, bg2, cw, nullptr);
        k_capacity<<<NBN_, 256, 0, stream>>>(cw, toks, wts, counts, nullptr, nullptr);
        for (int p = 0; p < NPF_; ++p) {
            k_fc1<<<NBN_ * 2, HCF_, 0, stream>>>(x, W1, b1, toks, counts, h, p);
            k_fc2<<<NBN_, 768, 0, stream>>>(W2, b2, toks, wts, counts, h, out, p);
        }
    }
}